// Round 1
// baseline (866.770 us; speedup 1.0000x reference)
//
#include <hip/hip_runtime.h>
#include <math.h>

typedef __attribute__((ext_vector_type(8))) __bf16 bf16x8;
typedef __attribute__((ext_vector_type(4))) float f32x4;

#define DEV static __device__ __forceinline__

DEV float b2f(unsigned short u){ union{unsigned i; float f;} c; c.i=((unsigned)u)<<16; return c.f; }
DEV unsigned short f2b(float f){
  union{float f; unsigned u;} c; c.f=f;
  unsigned r = 0x7FFFu + ((c.u>>16)&1u);
  return (unsigned short)((c.u + r)>>16);
}
DEV unsigned pack2(float a, float b){ return (unsigned)f2b(a) | ((unsigned)f2b(b)<<16); }
DEV float gelu_exact(float x){ return 0.5f*x*(1.f+erff(x*0.70710678118654752f)); }

// ---------------- elementwise cast fp32 -> bf16 (vectorized x4) ----------------
__global__ __launch_bounds__(256) void k_cast_bf16(const float* __restrict__ in,
                                                   unsigned short* __restrict__ out, long n4)
{
  long i = (long)blockIdx.x*256 + threadIdx.x;
  if (i >= n4) return;
  float4 v = ((const float4*)in)[i];
  ushort4 o; o.x=f2b(v.x); o.y=f2b(v.y); o.z=f2b(v.z); o.w=f2b(v.w);
  ((ushort4*)out)[i] = o;
}

// ---------------- transpose + cast: out[c][r] = bf16(in[r][c]) ----------------
__global__ __launch_bounds__(256) void k_transpose_cast(const float* __restrict__ in,
                                                        unsigned short* __restrict__ out,
                                                        int R, int C)
{
  __shared__ float tile[32][33];
  int tc = blockIdx.x*32, tr = blockIdx.y*32;
  int lx = threadIdx.x & 31, ly = threadIdx.x >> 5;
  #pragma unroll
  for (int s=0;s<4;s++) tile[ly+s*8][lx] = in[(long)(tr+ly+s*8)*C + tc+lx];
  __syncthreads();
  #pragma unroll
  for (int s=0;s<4;s++) out[(long)(tc+ly+s*8)*R + tr+lx] = f2b(tile[lx][ly+s*8]);
}

// ---------------- generic bf16 MFMA GEMM, B given transposed (Bt[n][k]) --------
// C[M,N] = A[M,K] * B[K,N] + bias;  tile BM=32*FM x BN=32*FN, 4 waves (2x2),
// per-wave FM x FN fragments of 16x16, BK=32 per iteration.
// OMODE: 0 = write fp32, 1 = write bf16, 2 = both.
template<int FM, int FN, int OMODE>
__global__ __launch_bounds__(256) void k_gemm_bt(
  const unsigned short* __restrict__ A, long lda, long sAb,
  const unsigned short* __restrict__ Bt, long ldb, long sBb,
  float* __restrict__ Cf, unsigned short* __restrict__ Cb, long ldc, long sCb,
  const float* __restrict__ bias, int Kiters)
{
  constexpr int BM = 32*FM, BN = 32*FN, LDSS = 40; // +8 pad breaks bank stride
  __shared__ __align__(16) unsigned short As[BM*LDSS];
  __shared__ __align__(16) unsigned short Bs[BN*LDSS];
  const int tid = threadIdx.x;
  const int wave = tid>>6, lane = tid&63;
  const int wr = wave>>1, wc = wave&1;
  const int l15 = lane&15, lhi = lane>>4;
  const long bm = (long)blockIdx.y*BM, bn = (long)blockIdx.x*BN;
  A  += (long)blockIdx.z*sAb;
  Bt += (long)blockIdx.z*sBb;

  f32x4 acc[FM][FN];
  #pragma unroll
  for (int i=0;i<FM;i++)
    #pragma unroll
    for (int j=0;j<FN;j++) acc[i][j] = (f32x4){0.f,0.f,0.f,0.f};

  for (int kt=0; kt<Kiters; ++kt) {
    const long k0 = (long)kt*32;
    #pragma unroll
    for (int c = tid; c < BM*4; c += 256) {      // BM*32/8 16B-chunks of A
      int row = c>>2, col = (c&3)*8;
      uint4 v = *(const uint4*)(A + (bm+row)*lda + k0 + col);
      *(uint4*)&As[row*LDSS + col] = v;
    }
    #pragma unroll
    for (int c = tid; c < BN*4; c += 256) {      // Bt chunks
      int row = c>>2, col = (c&3)*8;
      uint4 v = *(const uint4*)(Bt + (bn+row)*ldb + k0 + col);
      *(uint4*)&Bs[row*LDSS + col] = v;
    }
    __syncthreads();
    bf16x8 af[FM], bfr[FN];
    #pragma unroll
    for (int i=0;i<FM;i++)
      af[i] = *(const bf16x8*)&As[(wr*16*FM + i*16 + l15)*LDSS + lhi*8];
    #pragma unroll
    for (int j=0;j<FN;j++)
      bfr[j] = *(const bf16x8*)&Bs[(wc*16*FN + j*16 + l15)*LDSS + lhi*8];
    #pragma unroll
    for (int i=0;i<FM;i++)
      #pragma unroll
      for (int j=0;j<FN;j++)
        acc[i][j] = __builtin_amdgcn_mfma_f32_16x16x32_bf16(af[i], bfr[j], acc[i][j], 0,0,0);
    __syncthreads();
  }

  #pragma unroll
  for (int i=0;i<FM;i++) {
    #pragma unroll
    for (int j=0;j<FN;j++) {
      long col = bn + wc*16*FN + j*16 + l15;
      float bb = bias ? bias[col] : 0.f;
      #pragma unroll
      for (int q=0;q<4;q++) {
        long row = bm + wr*16*FM + i*16 + lhi*4 + q;
        float v = acc[i][j][q] + bb;
        long off = (long)blockIdx.z*sCb + row*ldc + col;
        if constexpr (OMODE==0 || OMODE==2) Cf[off] = v;
        if constexpr (OMODE==1 || OMODE==2) Cb[off] = f2b(v);
      }
    }
  }
}

// ---------------- top-16 + softmax weights per token ----------------
__global__ __launch_bounds__(256) void k_topk_softmax(const float* __restrict__ scores,
                                                      int* __restrict__ topidx,
                                                      float* __restrict__ topw)
{
  __shared__ float sv[2048];
  __shared__ float rv[256];
  __shared__ int   ri[256];
  __shared__ float selv[16];
  __shared__ int   seli[16];
  const int tid = threadIdx.x;
  const long t = blockIdx.x;
  const float* row = scores + t*2048;
  #pragma unroll
  for (int s=0;s<2;s++) ((float4*)sv)[tid + s*256] = ((const float4*)row)[tid + s*256];
  __syncthreads();
  for (int it=0; it<16; ++it) {
    float best = -1e30f; int bidx = 0x7FFFFFFF;
    #pragma unroll
    for (int s=0;s<8;s++) {
      int j = tid + s*256;
      float v = sv[j];
      if (v > best) { best = v; bidx = j; }   // ascending j: ties keep lowest idx
    }
    rv[tid]=best; ri[tid]=bidx;
    __syncthreads();
    for (int off=128; off>0; off>>=1) {
      if (tid < off) {
        float v2 = rv[tid+off]; int i2 = ri[tid+off];
        if (v2 > rv[tid] || (v2 == rv[tid] && i2 < ri[tid])) { rv[tid]=v2; ri[tid]=i2; }
      }
      __syncthreads();
    }
    if (tid == 0) { selv[it]=rv[0]; seli[it]=ri[0]; sv[ri[0]] = -1e30f; }
    __syncthreads();
  }
  if (tid == 0) {
    float m = selv[0], ssum = 0.f, w[16];
    #pragma unroll
    for (int k2=0;k2<16;k2++){ w[k2] = expf(selv[k2]-m); ssum += w[k2]; }
    float inv = 1.f/ssum;
    #pragma unroll
    for (int k2=0;k2<16;k2++){ topw[t*16+k2]=w[k2]*inv; topidx[t*16+k2]=seli[k2]; }
  }
}

// ---------------- gather firing rows, weighted combine, exact GELU -> bf16 -----
__global__ __launch_bounds__(256) void k_gather_gelu(const int* __restrict__ topidx,
                                                     const float* __restrict__ topw,
                                                     const unsigned short* __restrict__ firing,
                                                     unsigned short* __restrict__ gact)
{
  __shared__ int idx[16]; __shared__ float w[16];
  const int tid = threadIdx.x;
  const long t = blockIdx.x;
  if (tid < 16) { idx[tid] = topidx[t*16+tid]; w[tid] = topw[t*16+tid]; }
  __syncthreads();
  #pragma unroll
  for (int s=0;s<2;s++) {
    const int f0 = (tid + s*256)*8;
    float acc[8] = {0,0,0,0,0,0,0,0};
    for (int k=0;k<16;k++) {
      uint4 v = *(const uint4*)(firing + (long)idx[k]*4096 + f0);
      const unsigned short* pu = (const unsigned short*)&v;
      float wk = w[k];
      #pragma unroll
      for (int e=0;e<8;e++) acc[e] += wk * b2f(pu[e]);
    }
    float g[8];
    #pragma unroll
    for (int e=0;e<8;e++) g[e] = gelu_exact(acc[e]);
    uint4 ov;
    ov.x = pack2(g[0],g[1]); ov.y = pack2(g[2],g[3]);
    ov.z = pack2(g[4],g[5]); ov.w = pack2(g[6],g[7]);
    *(uint4*)(gact + t*4096 + f0) = ov;
  }
}

// ---------------- V transpose per (b,h): vT[bh][d][t] = qkv[b,t][2048+h*64+d] --
__global__ __launch_bounds__(256) void k_vtrans(const unsigned short* __restrict__ qkv,
                                                unsigned short* __restrict__ vT)
{
  __shared__ unsigned short tile[64][65];
  int bh = blockIdx.y; int b = bh>>4, h = bh&15;
  long t0 = (long)blockIdx.x*64;
  const int tid = threadIdx.x;
  #pragma unroll
  for (int s=0;s<16;s++) {
    int i = tid + s*256;
    int r = i>>6, c = i&63;
    tile[r][c] = qkv[ (long)(b*1024 + t0 + r)*3072 + 2048 + h*64 + c ];
  }
  __syncthreads();
  #pragma unroll
  for (int s=0;s<16;s++) {
    int i = tid + s*256;
    int c = i>>6, r = i&63;
    vT[ (long)bh*65536 + (long)c*1024 + t0 + r ] = tile[r][c];
  }
}

// ---------------- row softmax (with 1/8 scale) fp32 -> bf16 probs ----------------
__global__ __launch_bounds__(256) void k_softmax_row(const float* __restrict__ logits,
                                                     unsigned short* __restrict__ probs)
{
  const long r = blockIdx.x;
  const int tid = threadIdx.x;
  const int wave = tid>>6, lane = tid&63;
  float4 v = ((const float4*)(logits + r*1024))[tid];
  v.x*=0.125f; v.y*=0.125f; v.z*=0.125f; v.w*=0.125f;
  float m = fmaxf(fmaxf(v.x,v.y),fmaxf(v.z,v.w));
  #pragma unroll
  for (int off=32; off; off>>=1) m = fmaxf(m, __shfl_xor(m, off));
  __shared__ float wm[4], wsum[4];
  if (lane==0) wm[wave]=m;
  __syncthreads();
  m = fmaxf(fmaxf(wm[0],wm[1]),fmaxf(wm[2],wm[3]));
  float e0=expf(v.x-m), e1=expf(v.y-m), e2=expf(v.z-m), e3=expf(v.w-m);
  float s = e0+e1+e2+e3;
  #pragma unroll
  for (int off=32; off; off>>=1) s += __shfl_xor(s, off);
  if (lane==0) wsum[wave]=s;
  __syncthreads();
  s = wsum[0]+wsum[1]+wsum[2]+wsum[3];
  float inv = 1.f/s;
  ushort4 o; o.x=f2b(e0*inv); o.y=f2b(e1*inv); o.z=f2b(e2*inv); o.w=f2b(e3*inv);
  ((ushort4*)(probs + r*1024))[tid] = o;
}

// ---------------- residual + LayerNorm (row = 1024) ----------------
__global__ __launch_bounds__(256) void k_ln_res(const float* __restrict__ a,
                                                const float* b,          // may alias out
                                                const float* __restrict__ g,
                                                const float* __restrict__ be,
                                                float* out)
{
  const long t = blockIdx.x;
  const int tid = threadIdx.x;
  const int wave = tid>>6, lane = tid&63;
  float4 av = ((const float4*)(a + t*1024))[tid];
  float4 bv = ((const float4*)(b + t*1024))[tid];
  float4 sv = {av.x+bv.x, av.y+bv.y, av.z+bv.z, av.w+bv.w};
  float sum = sv.x+sv.y+sv.z+sv.w;
  float sq  = sv.x*sv.x + sv.y*sv.y + sv.z*sv.z + sv.w*sv.w;
  #pragma unroll
  for (int off=32; off; off>>=1){ sum += __shfl_xor(sum,off); sq += __shfl_xor(sq,off); }
  __shared__ float s1[4], s2[4];
  if (lane==0){ s1[wave]=sum; s2[wave]=sq; }
  __syncthreads();
  sum = s1[0]+s1[1]+s1[2]+s1[3];
  sq  = s2[0]+s2[1]+s2[2]+s2[3];
  float mu  = sum * (1.f/1024.f);
  float var = sq * (1.f/1024.f) - mu*mu;
  float rs  = rsqrtf(var + 1e-5f);
  float4 gv  = ((const float4*)g)[tid];
  float4 bev = ((const float4*)be)[tid];
  float4 ov = { (sv.x-mu)*rs*gv.x + bev.x,
                (sv.y-mu)*rs*gv.y + bev.y,
                (sv.z-mu)*rs*gv.z + bev.z,
                (sv.w-mu)*rs*gv.w + bev.w };
  ((float4*)(out + t*1024))[tid] = ov;
}

// =====================================================================
extern "C" void kernel_launch(void* const* d_in, const int* in_sizes, int n_in,
                              void* d_out, int out_size, void* d_ws, size_t ws_size,
                              hipStream_t stream)
{
  const float* x        = (const float*)d_in[0];
  const float* w_router = (const float*)d_in[1];
  const float* b_router = (const float*)d_in[2];
  const float* firing   = (const float*)d_in[3];
  const float* w_pool   = (const float*)d_in[4];
  const float* b_pool   = (const float*)d_in[5];
  const float* w_in     = (const float*)d_in[6];
  const float* b_in     = (const float*)d_in[7];
  const float* w_ao     = (const float*)d_in[8];
  const float* b_ao     = (const float*)d_in[9];
  const float* g1       = (const float*)d_in[10];
  const float* be1      = (const float*)d_in[11];
  const float* g2       = (const float*)d_in[12];
  const float* be2      = (const float*)d_in[13];
  float* out = (float*)d_out;
  char* ws = (char*)d_ws;

  // ws layout (bytes), ~189.3 MB peak with aliasing
  unsigned short* xb    = (unsigned short*)(ws + 0);          //  8,388,608
  unsigned short* wrT   = (unsigned short*)(ws + 8388608);    //  4,194,304
  unsigned short* firb  = (unsigned short*)(ws + 12582912);   // 16,777,216
  unsigned short* wpoT  = (unsigned short*)(ws + 29360128);   //  8,388,608
  unsigned short* winT  = (unsigned short*)(ws + 37748736);   //  6,291,456
  unsigned short* waoT  = (unsigned short*)(ws + 44040192);   //  2,097,152
  float*  scores        = (float*)(ws + 46137344);            // 33,554,432 (dead after topk)
  float*  logits        = (float*)(ws + 46137344);            // alias of scores (8 bh chunk)
  int*    topi          = (int*)(ws + 79691776);              //    262,144
  float*  topw          = (float*)(ws + 79953920);            //    262,144
  unsigned short* gact  = (unsigned short*)(ws + 80216064);   // 33,554,432 (dead after pool GEMM)
  unsigned short* probs = (unsigned short*)(ws + 80216064);   // alias (16,777,216 chunk)
  unsigned short* ctx   = (unsigned short*)(ws + 80216064 + 16777216); // 8,388,608
  float*  neuf          = (float*)(ws + 113770496);           // 16,777,216
  unsigned short* neub  = (unsigned short*)(ws + 130547712);  //  8,388,608
  unsigned short* qkvb  = (unsigned short*)(ws + 138936320);  // 25,165,824
  unsigned short* vT    = (unsigned short*)(ws + 164102144);  //  8,388,608
  float*  attn          = (float*)(ws + 172490752);           // 16,777,216 (h written in-place)

  if (ws_size < 189267968u) return; // insufficient scratch: fail loudly

  // ---- prep: bf16 casts + transposed bf16 weights ----
  k_cast_bf16<<<4096, 256, 0, stream>>>(x, xb, 4096L*1024/4);
  k_cast_bf16<<<8192, 256, 0, stream>>>(firing, firb, 2048L*4096/4);
  k_transpose_cast<<<dim3(2048/32, 1024/32), 256, 0, stream>>>(w_router, wrT, 1024, 2048);
  k_transpose_cast<<<dim3(1024/32, 4096/32), 256, 0, stream>>>(w_pool,   wpoT, 4096, 1024);
  k_transpose_cast<<<dim3(3072/32, 1024/32), 256, 0, stream>>>(w_in,     winT, 1024, 3072);
  k_transpose_cast<<<dim3(1024/32, 1024/32), 256, 0, stream>>>(w_ao,     waoT, 1024, 1024);

  // ---- router: scores = x @ w_router + b_router ----
  k_gemm_bt<4,4,0><<<dim3(16,32,1),256,0,stream>>>(xb,1024,0, wrT,1024,0,
        scores,nullptr,2048,0, b_router, 32);
  k_topk_softmax<<<4096,256,0,stream>>>(scores, topi, topw);
  k_gather_gelu<<<4096,256,0,stream>>>(topi, topw, firb, gact);

  // ---- pool: neuron_out = gelu(combined) @ w_pool_out + b_pool (f32 + bf16) ----
  k_gemm_bt<4,4,2><<<dim3(8,32,1),256,0,stream>>>(gact,4096,0, wpoT,4096,0,
        neuf,neub,1024,0, b_pool, 128);

  // ---- qkv = neuron_out @ w_in + b_in (bf16) ----
  k_gemm_bt<4,4,1><<<dim3(24,32,1),256,0,stream>>>(neub,1024,0, winT,1024,0,
        nullptr,qkvb,3072,0, b_in, 32);

  k_vtrans<<<dim3(16,64),256,0,stream>>>(qkvb, vT);

  // ---- attention, 8 chunks of (b, half-heads): 8 heads per chunk ----
  for (int c=0;c<8;c++) {
    int b = c>>1, hh = c&1;
    const unsigned short* qbase = qkvb + (long)b*3145728 + hh*512;
    const unsigned short* kbase = qkvb + (long)b*3145728 + 1024 + hh*512;
    k_gemm_bt<4,4,0><<<dim3(8,8,8),256,0,stream>>>(qbase,3072,64, kbase,3072,64,
          logits,nullptr,1024,1048576, nullptr, 2);
    k_softmax_row<<<8192,256,0,stream>>>(logits, probs);
    const unsigned short* vbase = vT + (long)(b*16 + hh*8)*65536;
    unsigned short* cbase = ctx + (long)b*1048576 + hh*512;
    k_gemm_bt<4,2,1><<<dim3(1,8,8),256,0,stream>>>(probs,1024,1048576, vbase,1024,65536,
          nullptr,cbase,1024,64, nullptr, 32);
  }

  // ---- attn_out = ctx @ w_attn_out + b_ao ----
  k_gemm_bt<4,4,0><<<dim3(8,32,1),256,0,stream>>>(ctx,1024,0, waoT,1024,0,
        attn,nullptr,1024,0, b_ao, 32);

  // ---- h = LN(x + attn) (in-place into attn); out = LN(h + neuron_out) ----
  k_ln_res<<<4096,256,0,stream>>>(x, attn, g1, be1, attn);
  k_ln_res<<<4096,256,0,stream>>>(attn, neuf, g2, be2, out);
}

// Round 2
// 581.871 us; speedup vs baseline: 1.4896x; 1.4896x over previous
//
#include <hip/hip_runtime.h>
#include <math.h>

typedef __attribute__((ext_vector_type(8))) __bf16 bf16x8;
typedef __attribute__((ext_vector_type(4))) float f32x4;

#define DEV static __device__ __forceinline__

DEV float b2f(unsigned short u){ union{unsigned i; float f;} c; c.i=((unsigned)u)<<16; return c.f; }
DEV unsigned short f2b(float f){
  union{float f; unsigned u;} c; c.f=f;
  unsigned r = 0x7FFFu + ((c.u>>16)&1u);
  return (unsigned short)((c.u + r)>>16);
}
DEV unsigned pack2(float a, float b){ return (unsigned)f2b(a) | ((unsigned)f2b(b)<<16); }
DEV float gelu_exact(float x){ return 0.5f*x*(1.f+erff(x*0.70710678118654752f)); }

typedef __attribute__((address_space(1))) void gas_void;
typedef __attribute__((address_space(3))) void las_void;
DEV void gload_lds16(const unsigned short* g, unsigned short* l){
  __builtin_amdgcn_global_load_lds((const gas_void*)g, (las_void*)l, 16, 0, 0);
}

// ---------------- elementwise cast fp32 -> bf16 (vectorized x4) ----------------
__global__ __launch_bounds__(256) void k_cast_bf16(const float* __restrict__ in,
                                                   unsigned short* __restrict__ out, long n4)
{
  long i = (long)blockIdx.x*256 + threadIdx.x;
  if (i >= n4) return;
  float4 v = ((const float4*)in)[i];
  ushort4 o; o.x=f2b(v.x); o.y=f2b(v.y); o.z=f2b(v.z); o.w=f2b(v.w);
  ((ushort4*)out)[i] = o;
}

// ---------------- transpose + cast: out[c][r] = bf16(in[r][c]) ----------------
__global__ __launch_bounds__(256) void k_transpose_cast(const float* __restrict__ in,
                                                        unsigned short* __restrict__ out,
                                                        int R, int C)
{
  __shared__ float tile[32][33];
  int tc = blockIdx.x*32, tr = blockIdx.y*32;
  int lx = threadIdx.x & 31, ly = threadIdx.x >> 5;
  #pragma unroll
  for (int s=0;s<4;s++) tile[ly+s*8][lx] = in[(long)(tr+ly+s*8)*C + tc+lx];
  __syncthreads();
  #pragma unroll
  for (int s=0;s<4;s++) out[(long)(tc+ly+s*8)*R + tr+lx] = f2b(tile[lx][ly+s*8]);
}

// ---------------- m97-structure bf16 MFMA GEMM, B transposed (Bt[n][k]) --------
// C[M,N] = A[M,K]*B[K,N] + bias. Tile BM=32*FM x BN=32*FN, 4 waves (2x2), each
// wave owns (BM/2)x(BN/2) = FM x FN 16x16 fragments. BK=32. Staging is
// global_load_lds width=16 into LINEAR LDS (row-major [rows][32] bf16).
// OMODE: 0 = fp32 out, 1 = bf16 out, 2 = both.
template<int FM, int FN, int OMODE>
__global__ __launch_bounds__(256) void k_gemm_bt(
  const unsigned short* __restrict__ A, long lda, long sAb,
  const unsigned short* __restrict__ Bt, long ldb, long sBb,
  float* __restrict__ Cf, unsigned short* __restrict__ Cb, long ldc, long sCb,
  const float* __restrict__ bias, int Kiters)
{
  constexpr int BM = 32*FM, BN = 32*FN;
  constexpr int AR16 = BM/16, TOT16 = (BM+BN)/16;   // 16-row stage units
  static_assert(TOT16 % 4 == 0, "stage units must split across 4 waves");
  __shared__ __align__(16) unsigned short S[(BM+BN)*32]; // A rows then B rows, linear
  const int tid = threadIdx.x;
  const int wave = tid>>6, lane = tid&63;
  const int wr = wave>>1, wc = wave&1;
  const int l15 = lane&15, lhi = lane>>4;
  const int lrow = lane>>2, lcol = (lane&3)*8;      // per-lane 16B within a 16-row stage
  const long bm = (long)blockIdx.y*BM, bn = (long)blockIdx.x*BN;
  const unsigned short* Ab  = A  + (long)blockIdx.z*sAb + bm*lda;
  const unsigned short* Btb = Bt + (long)blockIdx.z*sBb + bn*ldb;

  f32x4 acc[FM][FN];
  #pragma unroll
  for (int i=0;i<FM;i++)
    #pragma unroll
    for (int j=0;j<FN;j++) acc[i][j] = (f32x4){0.f,0.f,0.f,0.f};

  for (int kt=0; kt<Kiters; ++kt) {
    const long k0 = (long)kt*32;
    #pragma unroll
    for (int u=0; u<TOT16/4; ++u) {
      const int t = wave + u*4;                      // wave-uniform stage unit
      const unsigned short* g;
      if (t < AR16) g = Ab  + (long)(t*16 + lrow)*lda + k0 + lcol;
      else          g = Btb + (long)((t-AR16)*16 + lrow)*ldb + k0 + lcol;
      gload_lds16(g, &S[t*512]);                     // 16 rows x 32 el, linear
    }
    __syncthreads();                                 // drains vmcnt
    bf16x8 af[FM], bfr[FN];
    #pragma unroll
    for (int i=0;i<FM;i++)
      af[i]  = *(const bf16x8*)&S[(wr*(BM/2) + i*16 + l15)*32 + lhi*8];
    #pragma unroll
    for (int j=0;j<FN;j++)
      bfr[j] = *(const bf16x8*)&S[BM*32 + (wc*(BN/2) + j*16 + l15)*32 + lhi*8];
    #pragma unroll
    for (int i=0;i<FM;i++)
      #pragma unroll
      for (int j=0;j<FN;j++)
        acc[i][j] = __builtin_amdgcn_mfma_f32_16x16x32_bf16(af[i], bfr[j], acc[i][j], 0,0,0);
    __syncthreads();
  }

  #pragma unroll
  for (int i=0;i<FM;i++) {
    #pragma unroll
    for (int j=0;j<FN;j++) {
      long col = bn + wc*(BN/2) + j*16 + l15;
      float bb = bias ? bias[col] : 0.f;
      #pragma unroll
      for (int q=0;q<4;q++) {
        long row = bm + wr*(BM/2) + i*16 + lhi*4 + q;
        float v = acc[i][j][q] + bb;
        long off = (long)blockIdx.z*sCb + row*ldc + col;
        if constexpr (OMODE==0 || OMODE==2) Cf[off] = v;
        if constexpr (OMODE==1 || OMODE==2) Cb[off] = f2b(v);
      }
    }
  }
}

// ---------------- top-16 + softmax weights per token ----------------
__global__ __launch_bounds__(256) void k_topk_softmax(const float* __restrict__ scores,
                                                      int* __restrict__ topidx,
                                                      float* __restrict__ topw)
{
  __shared__ float sv[2048];
  __shared__ float rv[256];
  __shared__ int   ri[256];
  __shared__ float selv[16];
  __shared__ int   seli[16];
  const int tid = threadIdx.x;
  const long t = blockIdx.x;
  const float* row = scores + t*2048;
  #pragma unroll
  for (int s=0;s<2;s++) ((float4*)sv)[tid + s*256] = ((const float4*)row)[tid + s*256];
  __syncthreads();
  for (int it=0; it<16; ++it) {
    float best = -1e30f; int bidx = 0x7FFFFFFF;
    #pragma unroll
    for (int s=0;s<8;s++) {
      int j = tid + s*256;
      float v = sv[j];
      if (v > best) { best = v; bidx = j; }   // ascending j: ties keep lowest idx
    }
    rv[tid]=best; ri[tid]=bidx;
    __syncthreads();
    for (int off=128; off>0; off>>=1) {
      if (tid < off) {
        float v2 = rv[tid+off]; int i2 = ri[tid+off];
        if (v2 > rv[tid] || (v2 == rv[tid] && i2 < ri[tid])) { rv[tid]=v2; ri[tid]=i2; }
      }
      __syncthreads();
    }
    if (tid == 0) { selv[it]=rv[0]; seli[it]=ri[0]; sv[ri[0]] = -1e30f; }
    __syncthreads();
  }
  if (tid == 0) {
    float m = selv[0], ssum = 0.f, w[16];
    #pragma unroll
    for (int k2=0;k2<16;k2++){ w[k2] = expf(selv[k2]-m); ssum += w[k2]; }
    float inv = 1.f/ssum;
    #pragma unroll
    for (int k2=0;k2<16;k2++){ topw[t*16+k2]=w[k2]*inv; topidx[t*16+k2]=seli[k2]; }
  }
}

// ---------------- gather firing rows, weighted combine, exact GELU -> bf16 -----
__global__ __launch_bounds__(256) void k_gather_gelu(const int* __restrict__ topidx,
                                                     const float* __restrict__ topw,
                                                     const unsigned short* __restrict__ firing,
                                                     unsigned short* __restrict__ gact)
{
  __shared__ int idx[16]; __shared__ float w[16];
  const int tid = threadIdx.x;
  const long t = blockIdx.x;
  if (tid < 16) { idx[tid] = topidx[t*16+tid]; w[tid] = topw[t*16+tid]; }
  __syncthreads();
  #pragma unroll
  for (int s=0;s<2;s++) {
    const int f0 = (tid + s*256)*8;
    float acc[8] = {0,0,0,0,0,0,0,0};
    for (int k=0;k<16;k++) {
      uint4 v = *(const uint4*)(firing + (long)idx[k]*4096 + f0);
      const unsigned short* pu = (const unsigned short*)&v;
      float wk = w[k];
      #pragma unroll
      for (int e=0;e<8;e++) acc[e] += wk * b2f(pu[e]);
    }
    float g[8];
    #pragma unroll
    for (int e=0;e<8;e++) g[e] = gelu_exact(acc[e]);
    uint4 ov;
    ov.x = pack2(g[0],g[1]); ov.y = pack2(g[2],g[3]);
    ov.z = pack2(g[4],g[5]); ov.w = pack2(g[6],g[7]);
    *(uint4*)(gact + t*4096 + f0) = ov;
  }
}

// ---------------- V transpose per (b,h): vT[bh][d][t] = qkv[b,t][2048+h*64+d] --
__global__ __launch_bounds__(256) void k_vtrans(const unsigned short* __restrict__ qkv,
                                                unsigned short* __restrict__ vT)
{
  __shared__ unsigned short tile[64][65];
  int bh = blockIdx.y; int b = bh>>4, h = bh&15;
  long t0 = (long)blockIdx.x*64;
  const int tid = threadIdx.x;
  #pragma unroll
  for (int s=0;s<16;s++) {
    int i = tid + s*256;
    int r = i>>6, c = i&63;
    tile[r][c] = qkv[ (long)(b*1024 + t0 + r)*3072 + 2048 + h*64 + c ];
  }
  __syncthreads();
  #pragma unroll
  for (int s=0;s<16;s++) {
    int i = tid + s*256;
    int c = i>>6, r = i&63;
    vT[ (long)bh*65536 + (long)c*1024 + t0 + r ] = tile[r][c];
  }
}

// ------------- in-place row softmax (1/8 scale) over bf16 logits ----------------
__global__ __launch_bounds__(256) void k_softmax_row_bf16(unsigned short* __restrict__ logits)
{
  const long r = blockIdx.x;
  const int tid = threadIdx.x;
  const int wave = tid>>6, lane = tid&63;
  unsigned short* row = logits + r*1024;
  ushort4 u = ((const ushort4*)row)[tid];
  float v0 = b2f(u.x)*0.125f, v1 = b2f(u.y)*0.125f,
        v2 = b2f(u.z)*0.125f, v3 = b2f(u.w)*0.125f;
  float m = fmaxf(fmaxf(v0,v1),fmaxf(v2,v3));
  #pragma unroll
  for (int off=32; off; off>>=1) m = fmaxf(m, __shfl_xor(m, off));
  __shared__ float wm[4], wsum[4];
  if (lane==0) wm[wave]=m;
  __syncthreads();
  m = fmaxf(fmaxf(wm[0],wm[1]),fmaxf(wm[2],wm[3]));
  float e0=expf(v0-m), e1=expf(v1-m), e2=expf(v2-m), e3=expf(v3-m);
  float s = e0+e1+e2+e3;
  #pragma unroll
  for (int off=32; off; off>>=1) s += __shfl_xor(s, off);
  if (lane==0) wsum[wave]=s;
  __syncthreads();
  s = wsum[0]+wsum[1]+wsum[2]+wsum[3];
  float inv = 1.f/s;
  ushort4 o; o.x=f2b(e0*inv); o.y=f2b(e1*inv); o.z=f2b(e2*inv); o.w=f2b(e3*inv);
  ((ushort4*)row)[tid] = o;
}

// ---------------- residual + LayerNorm (row = 1024) ----------------
__global__ __launch_bounds__(256) void k_ln_res(const float* __restrict__ a,
                                                const float* b,          // may alias out
                                                const float* __restrict__ g,
                                                const float* __restrict__ be,
                                                float* out)
{
  const long t = blockIdx.x;
  const int tid = threadIdx.x;
  const int wave = tid>>6, lane = tid&63;
  float4 av = ((const float4*)(a + t*1024))[tid];
  float4 bv = ((const float4*)(b + t*1024))[tid];
  float4 sv = {av.x+bv.x, av.y+bv.y, av.z+bv.z, av.w+bv.w};
  float sum = sv.x+sv.y+sv.z+sv.w;
  float sq  = sv.x*sv.x + sv.y*sv.y + sv.z*sv.z + sv.w*sv.w;
  #pragma unroll
  for (int off=32; off; off>>=1){ sum += __shfl_xor(sum,off); sq += __shfl_xor(sq,off); }
  __shared__ float s1[4], s2[4];
  if (lane==0){ s1[wave]=sum; s2[wave]=sq; }
  __syncthreads();
  sum = s1[0]+s1[1]+s1[2]+s1[3];
  sq  = s2[0]+s2[1]+s2[2]+s2[3];
  float mu  = sum * (1.f/1024.f);
  float var = sq * (1.f/1024.f) - mu*mu;
  float rs  = rsqrtf(var + 1e-5f);
  float4 gv  = ((const float4*)g)[tid];
  float4 bev = ((const float4*)be)[tid];
  float4 ov = { (sv.x-mu)*rs*gv.x + bev.x,
                (sv.y-mu)*rs*gv.y + bev.y,
                (sv.z-mu)*rs*gv.z + bev.z,
                (sv.w-mu)*rs*gv.w + bev.w };
  ((float4*)(out + t*1024))[tid] = ov;
}

// =====================================================================
extern "C" void kernel_launch(void* const* d_in, const int* in_sizes, int n_in,
                              void* d_out, int out_size, void* d_ws, size_t ws_size,
                              hipStream_t stream)
{
  const float* x        = (const float*)d_in[0];
  const float* w_router = (const float*)d_in[1];
  const float* b_router = (const float*)d_in[2];
  const float* firing   = (const float*)d_in[3];
  const float* w_pool   = (const float*)d_in[4];
  const float* b_pool   = (const float*)d_in[5];
  const float* w_in     = (const float*)d_in[6];
  const float* b_in     = (const float*)d_in[7];
  const float* w_ao     = (const float*)d_in[8];
  const float* b_ao     = (const float*)d_in[9];
  const float* g1       = (const float*)d_in[10];
  const float* be1      = (const float*)d_in[11];
  const float* g2       = (const float*)d_in[12];
  const float* be2      = (const float*)d_in[13];
  float* out = (float*)d_out;
  char* ws = (char*)d_ws;

  // ws layout (bytes); P is triple-aliased: scores(f32,32MB) -> gact(bf16,32MB)
  // -> per-batch logits/probs(bf16,32MB). Total 164,102,144 B.
  unsigned short* xb    = (unsigned short*)(ws + 0);          //  8,388,608
  unsigned short* wrT   = (unsigned short*)(ws + 8388608);    //  4,194,304
  unsigned short* firb  = (unsigned short*)(ws + 12582912);   // 16,777,216
  unsigned short* wpoT  = (unsigned short*)(ws + 29360128);   //  8,388,608
  unsigned short* winT  = (unsigned short*)(ws + 37748736);   //  6,291,456
  unsigned short* waoT  = (unsigned short*)(ws + 44040192);   //  2,097,152
  float*  scores        = (float*)(ws + 46137344);            // 33,554,432 (P)
  unsigned short* gact  = (unsigned short*)(ws + 46137344);   // alias P
  unsigned short* lgts  = (unsigned short*)(ws + 46137344);   // alias P (per-batch)
  int*    topi          = (int*)(ws + 79691776);              //    262,144
  float*  topw          = (float*)(ws + 79953920);            //    262,144
  float*  neuf          = (float*)(ws + 80216064);            // 16,777,216
  unsigned short* neub  = (unsigned short*)(ws + 96993280);   //  8,388,608
  unsigned short* qkvb  = (unsigned short*)(ws + 105381888);  // 25,165,824
  unsigned short* vT    = (unsigned short*)(ws + 130547712);  //  8,388,608
  unsigned short* ctx   = (unsigned short*)(ws + 138936320);  //  8,388,608
  float*  attn          = (float*)(ws + 147324928);           // 16,777,216

  if (ws_size < 164102144u) return; // insufficient scratch: fail loudly

  // ---- prep: bf16 casts + transposed bf16 weights ----
  k_cast_bf16<<<4096, 256, 0, stream>>>(x, xb, 4096L*1024/4);
  k_cast_bf16<<<8192, 256, 0, stream>>>(firing, firb, 2048L*4096/4);
  k_transpose_cast<<<dim3(2048/32, 1024/32), 256, 0, stream>>>(w_router, wrT, 1024, 2048);
  k_transpose_cast<<<dim3(1024/32, 4096/32), 256, 0, stream>>>(w_pool,   wpoT, 4096, 1024);
  k_transpose_cast<<<dim3(3072/32, 1024/32), 256, 0, stream>>>(w_in,     winT, 1024, 3072);
  k_transpose_cast<<<dim3(1024/32, 1024/32), 256, 0, stream>>>(w_ao,     waoT, 1024, 1024);

  // ---- router: scores = x @ w_router + b_router ----
  k_gemm_bt<4,4,0><<<dim3(16,32,1),256,0,stream>>>(xb,1024,0, wrT,1024,0,
        scores,nullptr,2048,0, b_router, 32);
  k_topk_softmax<<<4096,256,0,stream>>>(scores, topi, topw);
  k_gather_gelu<<<4096,256,0,stream>>>(topi, topw, firb, gact);

  // ---- pool: neuron_out = gelu(combined) @ w_pool_out + b_pool (f32 + bf16) ----
  k_gemm_bt<4,4,2><<<dim3(8,32,1),256,0,stream>>>(gact,4096,0, wpoT,4096,0,
        neuf,neub,1024,0, b_pool, 128);

  // ---- qkv = neuron_out @ w_in + b_in (bf16) ----
  k_gemm_bt<4,4,1><<<dim3(24,32,1),256,0,stream>>>(neub,1024,0, winT,1024,0,
        nullptr,qkvb,3072,0, b_in, 32);

  k_vtrans<<<dim3(16,64),256,0,stream>>>(qkvb, vT);

  // ---- attention: 4 per-batch chunks of 16 heads, z = head ----
  for (int b=0;b<4;b++) {
    const unsigned short* qbase = qkvb + (long)b*3145728;
    const unsigned short* kbase = qkvb + (long)b*3145728 + 1024;
    // logits[h][t][t'] bf16 (scaled later in softmax)
    k_gemm_bt<4,4,1><<<dim3(8,8,16),256,0,stream>>>(qbase,3072,64, kbase,3072,64,
          nullptr,lgts,1024,1048576, nullptr, 2);
    k_softmax_row_bf16<<<16384,256,0,stream>>>(lgts);
    const unsigned short* vbase = vT + (long)b*16*65536;
    unsigned short* cbase = ctx + (long)b*1048576;
    k_gemm_bt<4,2,1><<<dim3(1,8,16),256,0,stream>>>(lgts,1024,1048576, vbase,1024,65536,
          nullptr,cbase,1024,64, nullptr, 32);
  }

  // ---- attn_out = ctx @ w_attn_out + b_ao ----
  k_gemm_bt<4,4,0><<<dim3(8,32,1),256,0,stream>>>(ctx,1024,0, waoT,1024,0,
        attn,nullptr,1024,0, b_ao, 32);

  // ---- h = LN(x + attn) (in-place into attn); out = LN(h + neuron_out) ----
  k_ln_res<<<4096,256,0,stream>>>(x, attn, g1, be1, attn);
  k_ln_res<<<4096,256,0,stream>>>(attn, neuf, g2, be2, out);
}

// Round 3
// 489.697 us; speedup vs baseline: 1.7700x; 1.1882x over previous
//
#include <hip/hip_runtime.h>
#include <math.h>

typedef __attribute__((ext_vector_type(8))) __bf16 bf16x8;
typedef __attribute__((ext_vector_type(4))) float f32x4;

#define DEV static __device__ __forceinline__

DEV float b2f(unsigned short u){ union{unsigned i; float f;} c; c.i=((unsigned)u)<<16; return c.f; }
DEV unsigned short f2b(float f){
  union{float f; unsigned u;} c; c.f=f;
  unsigned r = 0x7FFFu + ((c.u>>16)&1u);
  return (unsigned short)((c.u + r)>>16);
}
DEV unsigned pack2(float a, float b){ return (unsigned)f2b(a) | ((unsigned)f2b(b)<<16); }
DEV float gelu_exact(float x){ return 0.5f*x*(1.f+erff(x*0.70710678118654752f)); }

typedef __attribute__((address_space(1))) void gas_void;
typedef __attribute__((address_space(3))) void las_void;
DEV void gload_lds16(const unsigned short* g, unsigned short* l){
  __builtin_amdgcn_global_load_lds((const gas_void*)g, (las_void*)l, 16, 0, 0);
}

// ---------------- elementwise cast fp32 -> bf16 (vectorized x4) ----------------
__global__ __launch_bounds__(256) void k_cast_bf16(const float* __restrict__ in,
                                                   unsigned short* __restrict__ out, long n4)
{
  long i = (long)blockIdx.x*256 + threadIdx.x;
  if (i >= n4) return;
  float4 v = ((const float4*)in)[i];
  ushort4 o; o.x=f2b(v.x); o.y=f2b(v.y); o.z=f2b(v.z); o.w=f2b(v.w);
  ((ushort4*)out)[i] = o;
}

// ---------------- transpose + cast: out[c][r] = bf16(in[r][c]) ----------------
__global__ __launch_bounds__(256) void k_transpose_cast(const float* __restrict__ in,
                                                        unsigned short* __restrict__ out,
                                                        int R, int C)
{
  __shared__ float tile[32][33];
  int tc = blockIdx.x*32, tr = blockIdx.y*32;
  int lx = threadIdx.x & 31, ly = threadIdx.x >> 5;
  #pragma unroll
  for (int s=0;s<4;s++) tile[ly+s*8][lx] = in[(long)(tr+ly+s*8)*C + tc+lx];
  __syncthreads();
  #pragma unroll
  for (int s=0;s<4;s++) out[(long)(tc+ly+s*8)*R + tr+lx] = f2b(tile[lx][ly+s*8]);
}

// ------- 2-phase double-buffered bf16 MFMA GEMM, B transposed (Bt[n][k]) -------
// C[M,N] = A[M,K]*B[K,N] + bias. Tile BM=32*FM x BN=32*FN, 4 waves (2x2), each
// wave owns FM x FN 16x16 fragments. BK=32. Staging: global_load_lds width=16
// into LINEAR LDS, double-buffered; next tile's loads in flight during MFMA
// (T3-minimum 2-phase). XCD-aware bijective block swizzle (T1), nwg%8==0.
// OMODE: 0 = fp32 out, 1 = bf16 out, 2 = both.
template<int FM, int FN, int OMODE>
__global__ __launch_bounds__(256) void k_gemm_bt(
  const unsigned short* __restrict__ A, long lda, long sAb,
  const unsigned short* __restrict__ Bt, long ldb, long sBb,
  float* __restrict__ Cf, unsigned short* __restrict__ Cb, long ldc, long sCb,
  const float* __restrict__ bias, int Kiters)
{
  constexpr int BM = 32*FM, BN = 32*FN;
  constexpr int AR16 = BM/16, TOT16 = (BM+BN)/16;   // 16-row stage units
  constexpr int UNITS = TOT16/4;
  static_assert(TOT16 % 4 == 0, "stage units must split across 4 waves");
  __shared__ __align__(16) unsigned short S[2][TOT16*512]; // [buf][A rows | B rows]
  const int tid = threadIdx.x;
  const int wave = tid>>6, lane = tid&63;
  const int wr = wave>>1, wc = wave&1;
  const int l15 = lane&15, lhi = lane>>4;
  const int lrow = lane>>2, lcol = (lane&3)*8;      // per-lane 16B within a 16-row unit

  // XCD-aware bijective swizzle within the z-slice (requires gx*gy % 8 == 0)
  const int gx = gridDim.x;
  const int nwg = gx*gridDim.y;
  const int id = blockIdx.y*gx + blockIdx.x;
  const int sid = (id&7)*(nwg>>3) + (id>>3);
  const long bm = (long)(sid / gx)*BM, bn = (long)(sid % gx)*BN;

  const unsigned short* Ab  = A  + (long)blockIdx.z*sAb + bm*lda;
  const unsigned short* Btb = Bt + (long)blockIdx.z*sBb + bn*ldb;

  f32x4 acc[FM][FN];
  #pragma unroll
  for (int i=0;i<FM;i++)
    #pragma unroll
    for (int j=0;j<FN;j++) acc[i][j] = (f32x4){0.f,0.f,0.f,0.f};

  auto STAGE = [&](int kt, int buf){
    const long k0 = (long)kt*32;
    #pragma unroll
    for (int u=0; u<UNITS; ++u) {
      const int t = wave + u*4;                      // wave-uniform stage unit
      const unsigned short* g;
      if (t < AR16) g = Ab  + (long)(t*16 + lrow)*lda + k0 + lcol;
      else          g = Btb + (long)((t-AR16)*16 + lrow)*ldb + k0 + lcol;
      gload_lds16(g, &S[buf][t*512]);                // 16 rows x 32 el, linear
    }
  };
  auto COMPUTE = [&](int buf){
    const unsigned short* Sb = S[buf];
    bf16x8 af[FM], bfr[FN];
    #pragma unroll
    for (int i=0;i<FM;i++)
      af[i]  = *(const bf16x8*)&Sb[(wr*(BM/2) + i*16 + l15)*32 + lhi*8];
    #pragma unroll
    for (int j=0;j<FN;j++)
      bfr[j] = *(const bf16x8*)&Sb[BM*32 + (wc*(BN/2) + j*16 + l15)*32 + lhi*8];
    #pragma unroll
    for (int i=0;i<FM;i++)
      #pragma unroll
      for (int j=0;j<FN;j++)
        acc[i][j] = __builtin_amdgcn_mfma_f32_16x16x32_bf16(af[i], bfr[j], acc[i][j], 0,0,0);
  };

  STAGE(0, 0);
  __syncthreads();                                   // vmcnt(0): tile 0 resident
  int cur = 0;
  for (int kt=0; kt<Kiters-1; ++kt) {
    STAGE(kt+1, cur^1);                              // next tile in flight...
    COMPUTE(cur);                                    // ...under current compute
    __syncthreads();                                 // vmcnt(0) + reuse-safety
    cur ^= 1;
  }
  COMPUTE(cur);                                      // epilogue tile, no prefetch

  #pragma unroll
  for (int i=0;i<FM;i++) {
    #pragma unroll
    for (int j=0;j<FN;j++) {
      long col = bn + wc*(BN/2) + j*16 + l15;
      float bb = bias ? bias[col] : 0.f;
      #pragma unroll
      for (int q=0;q<4;q++) {
        long row = bm + wr*(BM/2) + i*16 + lhi*4 + q;
        float v = acc[i][j][q] + bb;
        long off = (long)blockIdx.z*sCb + row*ldc + col;
        if constexpr (OMODE==0 || OMODE==2) Cf[off] = v;
        if constexpr (OMODE==1 || OMODE==2) Cb[off] = f2b(v);
      }
    }
  }
}

// ---------------- top-16 + softmax weights per token ----------------
__global__ __launch_bounds__(256) void k_topk_softmax(const float* __restrict__ scores,
                                                      int* __restrict__ topidx,
                                                      float* __restrict__ topw)
{
  __shared__ float sv[2048];
  __shared__ float rv[256];
  __shared__ int   ri[256];
  __shared__ float selv[16];
  __shared__ int   seli[16];
  const int tid = threadIdx.x;
  const long t = blockIdx.x;
  const float* row = scores + t*2048;
  #pragma unroll
  for (int s=0;s<2;s++) ((float4*)sv)[tid + s*256] = ((const float4*)row)[tid + s*256];
  __syncthreads();
  for (int it=0; it<16; ++it) {
    float best = -1e30f; int bidx = 0x7FFFFFFF;
    #pragma unroll
    for (int s=0;s<8;s++) {
      int j = tid + s*256;
      float v = sv[j];
      if (v > best) { best = v; bidx = j; }   // ascending j: ties keep lowest idx
    }
    rv[tid]=best; ri[tid]=bidx;
    __syncthreads();
    if (tid < 64) {
      float bv = rv[tid]; int bi = ri[tid];
      #pragma unroll
      for (int s=1;s<4;s++) {
        float v2 = rv[tid+64*s]; int i2 = ri[tid+64*s];
        if (v2 > bv || (v2 == bv && i2 < bi)) { bv=v2; bi=i2; }
      }
      #pragma unroll
      for (int off=32; off; off>>=1) {
        float v2 = __shfl_xor(bv, off); int i2 = __shfl_xor(bi, off);
        if (v2 > bv || (v2 == bv && i2 < bi)) { bv=v2; bi=i2; }
      }
      if (tid == 0) { selv[it]=bv; seli[it]=bi; sv[bi] = -1e30f; }
    }
    __syncthreads();
  }
  if (tid == 0) {
    float m = selv[0], ssum = 0.f, w[16];
    #pragma unroll
    for (int k2=0;k2<16;k2++){ w[k2] = expf(selv[k2]-m); ssum += w[k2]; }
    float inv = 1.f/ssum;
    #pragma unroll
    for (int k2=0;k2<16;k2++){ topw[t*16+k2]=w[k2]*inv; topidx[t*16+k2]=seli[k2]; }
  }
}

// ---------------- gather firing rows, weighted combine, exact GELU -> bf16 -----
__global__ __launch_bounds__(256) void k_gather_gelu(const int* __restrict__ topidx,
                                                     const float* __restrict__ topw,
                                                     const unsigned short* __restrict__ firing,
                                                     unsigned short* __restrict__ gact)
{
  __shared__ int idx[16]; __shared__ float w[16];
  const int tid = threadIdx.x;
  const long t = blockIdx.x;
  if (tid < 16) { idx[tid] = topidx[t*16+tid]; w[tid] = topw[t*16+tid]; }
  __syncthreads();
  #pragma unroll
  for (int s=0;s<2;s++) {
    const int f0 = (tid + s*256)*8;
    float acc[8] = {0,0,0,0,0,0,0,0};
    for (int k=0;k<16;k++) {
      uint4 v = *(const uint4*)(firing + (long)idx[k]*4096 + f0);
      const unsigned short* pu = (const unsigned short*)&v;
      float wk = w[k];
      #pragma unroll
      for (int e=0;e<8;e++) acc[e] += wk * b2f(pu[e]);
    }
    float g[8];
    #pragma unroll
    for (int e=0;e<8;e++) g[e] = gelu_exact(acc[e]);
    uint4 ov;
    ov.x = pack2(g[0],g[1]); ov.y = pack2(g[2],g[3]);
    ov.z = pack2(g[4],g[5]); ov.w = pack2(g[6],g[7]);
    *(uint4*)(gact + t*4096 + f0) = ov;
  }
}

// ---------------- V transpose per (b,h): vT[bh][d][t] = qkv[b,t][2048+h*64+d] --
__global__ __launch_bounds__(256) void k_vtrans(const unsigned short* __restrict__ qkv,
                                                unsigned short* __restrict__ vT)
{
  __shared__ unsigned short tile[64][65];
  int bh = blockIdx.y; int b = bh>>4, h = bh&15;
  long t0 = (long)blockIdx.x*64;
  const int tid = threadIdx.x;
  #pragma unroll
  for (int s=0;s<16;s++) {
    int i = tid + s*256;
    int r = i>>6, c = i&63;
    tile[r][c] = qkv[ (long)(b*1024 + t0 + r)*3072 + 2048 + h*64 + c ];
  }
  __syncthreads();
  #pragma unroll
  for (int s=0;s<16;s++) {
    int i = tid + s*256;
    int c = i>>6, r = i&63;
    vT[ (long)bh*65536 + (long)c*1024 + t0 + r ] = tile[r][c];
  }
}

// ------------- in-place row softmax (1/8 scale) over bf16 logits ----------------
__global__ __launch_bounds__(256) void k_softmax_row_bf16(unsigned short* __restrict__ logits)
{
  const long r = blockIdx.x;
  const int tid = threadIdx.x;
  const int wave = tid>>6, lane = tid&63;
  unsigned short* row = logits + r*1024;
  ushort4 u = ((const ushort4*)row)[tid];
  float v0 = b2f(u.x)*0.125f, v1 = b2f(u.y)*0.125f,
        v2 = b2f(u.z)*0.125f, v3 = b2f(u.w)*0.125f;
  float m = fmaxf(fmaxf(v0,v1),fmaxf(v2,v3));
  #pragma unroll
  for (int off=32; off; off>>=1) m = fmaxf(m, __shfl_xor(m, off));
  __shared__ float wm[4], wsum[4];
  if (lane==0) wm[wave]=m;
  __syncthreads();
  m = fmaxf(fmaxf(wm[0],wm[1]),fmaxf(wm[2],wm[3]));
  float e0=expf(v0-m), e1=expf(v1-m), e2=expf(v2-m), e3=expf(v3-m);
  float s = e0+e1+e2+e3;
  #pragma unroll
  for (int off=32; off; off>>=1) s += __shfl_xor(s, off);
  if (lane==0) wsum[wave]=s;
  __syncthreads();
  s = wsum[0]+wsum[1]+wsum[2]+wsum[3];
  float inv = 1.f/s;
  ushort4 o; o.x=f2b(e0*inv); o.y=f2b(e1*inv); o.z=f2b(e2*inv); o.w=f2b(e3*inv);
  ((ushort4*)row)[tid] = o;
}

// ---------------- residual + LayerNorm (row = 1024) ----------------
__global__ __launch_bounds__(256) void k_ln_res(const float* __restrict__ a,
                                                const float* b,          // may alias out
                                                const float* __restrict__ g,
                                                const float* __restrict__ be,
                                                float* out)
{
  const long t = blockIdx.x;
  const int tid = threadIdx.x;
  const int wave = tid>>6, lane = tid&63;
  float4 av = ((const float4*)(a + t*1024))[tid];
  float4 bv = ((const float4*)(b + t*1024))[tid];
  float4 sv = {av.x+bv.x, av.y+bv.y, av.z+bv.z, av.w+bv.w};
  float sum = sv.x+sv.y+sv.z+sv.w;
  float sq  = sv.x*sv.x + sv.y*sv.y + sv.z*sv.z + sv.w*sv.w;
  #pragma unroll
  for (int off=32; off; off>>=1){ sum += __shfl_xor(sum,off); sq += __shfl_xor(sq,off); }
  __shared__ float s1[4], s2[4];
  if (lane==0){ s1[wave]=sum; s2[wave]=sq; }
  __syncthreads();
  sum = s1[0]+s1[1]+s1[2]+s1[3];
  sq  = s2[0]+s2[1]+s2[2]+s2[3];
  float mu  = sum * (1.f/1024.f);
  float var = sq * (1.f/1024.f) - mu*mu;
  float rs  = rsqrtf(var + 1e-5f);
  float4 gv  = ((const float4*)g)[tid];
  float4 bev = ((const float4*)be)[tid];
  float4 ov = { (sv.x-mu)*rs*gv.x + bev.x,
                (sv.y-mu)*rs*gv.y + bev.y,
                (sv.z-mu)*rs*gv.z + bev.z,
                (sv.w-mu)*rs*gv.w + bev.w };
  ((float4*)(out + t*1024))[tid] = ov;
}

// =====================================================================
extern "C" void kernel_launch(void* const* d_in, const int* in_sizes, int n_in,
                              void* d_out, int out_size, void* d_ws, size_t ws_size,
                              hipStream_t stream)
{
  const float* x        = (const float*)d_in[0];
  const float* w_router = (const float*)d_in[1];
  const float* b_router = (const float*)d_in[2];
  const float* firing   = (const float*)d_in[3];
  const float* w_pool   = (const float*)d_in[4];
  const float* b_pool   = (const float*)d_in[5];
  const float* w_in     = (const float*)d_in[6];
  const float* b_in     = (const float*)d_in[7];
  const float* w_ao     = (const float*)d_in[8];
  const float* b_ao     = (const float*)d_in[9];
  const float* g1       = (const float*)d_in[10];
  const float* be1      = (const float*)d_in[11];
  const float* g2       = (const float*)d_in[12];
  const float* be2      = (const float*)d_in[13];
  float* out = (float*)d_out;
  char* ws = (char*)d_ws;

  // ws layout (bytes); P is triple-aliased: scores(f32,32MB) -> gact(bf16,32MB)
  // -> per-batch logits/probs(bf16,32MB). Total 164,102,144 B.
  unsigned short* xb    = (unsigned short*)(ws + 0);          //  8,388,608
  unsigned short* wrT   = (unsigned short*)(ws + 8388608);    //  4,194,304
  unsigned short* firb  = (unsigned short*)(ws + 12582912);   // 16,777,216
  unsigned short* wpoT  = (unsigned short*)(ws + 29360128);   //  8,388,608
  unsigned short* winT  = (unsigned short*)(ws + 37748736);   //  6,291,456
  unsigned short* waoT  = (unsigned short*)(ws + 44040192);   //  2,097,152
  float*  scores        = (float*)(ws + 46137344);            // 33,554,432 (P)
  unsigned short* gact  = (unsigned short*)(ws + 46137344);   // alias P
  unsigned short* lgts  = (unsigned short*)(ws + 46137344);   // alias P (per-batch)
  int*    topi          = (int*)(ws + 79691776);              //    262,144
  float*  topw          = (float*)(ws + 79953920);            //    262,144
  float*  neuf          = (float*)(ws + 80216064);            // 16,777,216
  unsigned short* neub  = (unsigned short*)(ws + 96993280);   //  8,388,608
  unsigned short* qkvb  = (unsigned short*)(ws + 105381888);  // 25,165,824
  unsigned short* vT    = (unsigned short*)(ws + 130547712);  //  8,388,608
  unsigned short* ctx   = (unsigned short*)(ws + 138936320);  //  8,388,608
  float*  attn          = (float*)(ws + 147324928);           // 16,777,216

  if (ws_size < 164102144u) return; // insufficient scratch: fail loudly

  // ---- prep: bf16 casts + transposed bf16 weights ----
  k_cast_bf16<<<4096, 256, 0, stream>>>(x, xb, 4096L*1024/4);
  k_cast_bf16<<<8192, 256, 0, stream>>>(firing, firb, 2048L*4096/4);
  k_transpose_cast<<<dim3(2048/32, 1024/32), 256, 0, stream>>>(w_router, wrT, 1024, 2048);
  k_transpose_cast<<<dim3(1024/32, 4096/32), 256, 0, stream>>>(w_pool,   wpoT, 4096, 1024);
  k_transpose_cast<<<dim3(3072/32, 1024/32), 256, 0, stream>>>(w_in,     winT, 1024, 3072);
  k_transpose_cast<<<dim3(1024/32, 1024/32), 256, 0, stream>>>(w_ao,     waoT, 1024, 1024);

  // ---- router: scores = x @ w_router + b_router (128x128 tiles, 512 wg) ----
  k_gemm_bt<4,4,0><<<dim3(16,32,1),256,0,stream>>>(xb,1024,0, wrT,1024,0,
        scores,nullptr,2048,0, b_router, 32);
  k_topk_softmax<<<4096,256,0,stream>>>(scores, topi, topw);
  k_gather_gelu<<<4096,256,0,stream>>>(topi, topw, firb, gact);

  // ---- pool: neuron_out = gelu(combined) @ w_pool_out + b_pool (128x64, 512 wg) ----
  k_gemm_bt<4,2,2><<<dim3(16,32,1),256,0,stream>>>(gact,4096,0, wpoT,4096,0,
        neuf,neub,1024,0, b_pool, 128);

  // ---- qkv = neuron_out @ w_in + b_in (bf16; 128x128, 768 wg) ----
  k_gemm_bt<4,4,1><<<dim3(24,32,1),256,0,stream>>>(neub,1024,0, winT,1024,0,
        nullptr,qkvb,3072,0, b_in, 32);

  k_vtrans<<<dim3(16,64),256,0,stream>>>(qkvb, vT);

  // ---- attention: 4 per-batch chunks of 16 heads, z = head ----
  for (int b=0;b<4;b++) {
    const unsigned short* qbase = qkvb + (long)b*3145728;
    const unsigned short* kbase = qkvb + (long)b*3145728 + 1024;
    // logits[h][t][t'] bf16 (scaled later in softmax)
    k_gemm_bt<4,4,1><<<dim3(8,8,16),256,0,stream>>>(qbase,3072,64, kbase,3072,64,
          nullptr,lgts,1024,1048576, nullptr, 2);
    k_softmax_row_bf16<<<16384,256,0,stream>>>(lgts);
    const unsigned short* vbase = vT + (long)b*16*65536;
    unsigned short* cbase = ctx + (long)b*1048576;
    // PV: 64x64 tiles -> 256 wg per batch
    k_gemm_bt<2,2,1><<<dim3(1,16,16),256,0,stream>>>(lgts,1024,1048576, vbase,1024,65536,
          nullptr,cbase,1024,64, nullptr, 32);
  }

  // ---- attn_out = ctx @ w_attn_out + b_ao (128x64, 512 wg) ----
  k_gemm_bt<4,2,0><<<dim3(16,32,1),256,0,stream>>>(ctx,1024,0, waoT,1024,0,
        attn,nullptr,1024,0, b_ao, 32);

  // ---- h = LN(x + attn) (in-place into attn); out = LN(h + neuron_out) ----
  k_ln_res<<<4096,256,0,stream>>>(x, attn, g1, be1, attn);
  k_ln_res<<<4096,256,0,stream>>>(attn, neuf, g2, be2, out);
}

// Round 4
// 452.170 us; speedup vs baseline: 1.9169x; 1.0830x over previous
//
#include <hip/hip_runtime.h>
#include <math.h>

typedef __attribute__((ext_vector_type(8))) __bf16 bf16x8;
typedef __attribute__((ext_vector_type(4))) float f32x4;

#define DEV static __device__ __forceinline__

DEV float b2f(unsigned short u){ union{unsigned i; float f;} c; c.i=((unsigned)u)<<16; return c.f; }
DEV unsigned short f2b(float f){
  union{float f; unsigned u;} c; c.f=f;
  unsigned r = 0x7FFFu + ((c.u>>16)&1u);
  return (unsigned short)((c.u + r)>>16);
}
DEV unsigned pack2(float a, float b){ return (unsigned)f2b(a) | ((unsigned)f2b(b)<<16); }
DEV float gelu_exact(float x){ return 0.5f*x*(1.f+erff(x*0.70710678118654752f)); }

typedef __attribute__((address_space(1))) void gas_void;
typedef __attribute__((address_space(3))) void las_void;
DEV void gload_lds16(const unsigned short* g, unsigned short* l){
  __builtin_amdgcn_global_load_lds((const gas_void*)g, (las_void*)l, 16, 0, 0);
}

template<int N> DEV void waitcnt_vm(){
  if constexpr(N==0) asm volatile("s_waitcnt vmcnt(0)" ::: "memory");
  else if constexpr(N==2) asm volatile("s_waitcnt vmcnt(2)" ::: "memory");
  else if constexpr(N==3) asm volatile("s_waitcnt vmcnt(3)" ::: "memory");
  else if constexpr(N==4) asm volatile("s_waitcnt vmcnt(4)" ::: "memory");
  else                    asm volatile("s_waitcnt vmcnt(0)" ::: "memory");
}

// ---------------- elementwise cast fp32 -> bf16 (vectorized x4) ----------------
__global__ __launch_bounds__(256) void k_cast_bf16(const float* __restrict__ in,
                                                   unsigned short* __restrict__ out, long n4)
{
  long i = (long)blockIdx.x*256 + threadIdx.x;
  if (i >= n4) return;
  float4 v = ((const float4*)in)[i];
  ushort4 o; o.x=f2b(v.x); o.y=f2b(v.y); o.z=f2b(v.z); o.w=f2b(v.w);
  ((ushort4*)out)[i] = o;
}

// ---------------- transpose + cast: out[c][r] = bf16(in[r][c]) ----------------
__global__ __launch_bounds__(256) void k_transpose_cast(const float* __restrict__ in,
                                                        unsigned short* __restrict__ out,
                                                        int R, int C)
{
  __shared__ float tile[32][33];
  int tc = blockIdx.x*32, tr = blockIdx.y*32;
  int lx = threadIdx.x & 31, ly = threadIdx.x >> 5;
  #pragma unroll
  for (int s=0;s<4;s++) tile[ly+s*8][lx] = in[(long)(tr+ly+s*8)*C + tc+lx];
  __syncthreads();
  #pragma unroll
  for (int s=0;s<4;s++) out[(long)(tc+ly+s*8)*R + tr+lx] = f2b(tile[lx][ly+s*8]);
}

// -- 3-buffer counted-vmcnt bf16 MFMA GEMM (T3-min + T4), B transposed Bt[n][k] --
// C[M,N] = A[M,K]*B[K,N] + bias. Tile BM=32*FM x BN=32*FN, 4 waves (2x2), each
// wave owns FM x FN 16x16 fragments. BK=32. Staging: global_load_lds width=16,
// triple-buffered; raw s_barrier + counted s_waitcnt vmcnt(UNITS) keeps the
// next tile's loads in flight across the barrier (never drain to 0 mid-loop).
// T2 slot-XOR: pre-swizzled global source col + XOR'd ds_read slot (rule #21).
// T1 bijective XCD swizzle (requires gridDim.x*gridDim.y % 8 == 0).
// OMODE: 0 = fp32 out, 1 = bf16 out, 2 = both.
template<int FM, int FN, int OMODE>
__global__ __launch_bounds__(256) void k_gemm_bt(
  const unsigned short* __restrict__ A, long lda, long sAb,
  const unsigned short* __restrict__ Bt, long ldb, long sBb,
  float* __restrict__ Cf, unsigned short* __restrict__ Cb, long ldc, long sCb,
  const float* __restrict__ bias, int Kiters)
{
  constexpr int BM = 32*FM, BN = 32*FN;
  constexpr int AR16 = BM/16, TOT16 = (BM+BN)/16;   // 16-row stage units
  constexpr int UNITS = TOT16/4;                    // gload_lds per wave per tile
  static_assert(TOT16 % 4 == 0, "stage units must split across 4 waves");
  __shared__ __align__(16) unsigned short S[3][TOT16*512];
  const int tid = threadIdx.x;
  const int wave = tid>>6, lane = tid&63;
  const int wr = wave>>1, wc = wave&1;
  const int l15 = lane&15, lhi = lane>>4;
  const int lrow = lane>>2;
  const int lcol = ((lane&3) ^ (lrow&3))*8;         // T2 pre-swizzled source slot

  // XCD-aware bijective swizzle within the z-slice
  const int gx = gridDim.x;
  const int nwg = gx*gridDim.y;
  const int id = blockIdx.y*gx + blockIdx.x;
  const int sid = (id&7)*(nwg>>3) + (id>>3);
  const long bm = (long)(sid / gx)*BM, bn = (long)(sid % gx)*BN;

  const unsigned short* Ab  = A  + (long)blockIdx.z*sAb + bm*lda;
  const unsigned short* Btb = Bt + (long)blockIdx.z*sBb + bn*ldb;

  f32x4 acc[FM][FN];
  #pragma unroll
  for (int i=0;i<FM;i++)
    #pragma unroll
    for (int j=0;j<FN;j++) acc[i][j] = (f32x4){0.f,0.f,0.f,0.f};

  auto STAGE = [&](int kt, int buf){
    const long k0 = (long)kt*32;
    #pragma unroll
    for (int u=0; u<UNITS; ++u) {
      const int t = wave + u*4;                      // wave-uniform stage unit
      const unsigned short* g;
      if (t < AR16) g = Ab  + (long)(t*16 + lrow)*lda + k0 + lcol;
      else          g = Btb + (long)((t-AR16)*16 + lrow)*ldb + k0 + lcol;
      gload_lds16(g, &S[buf][t*512]);                // linear dest, swz source
    }
  };
  auto COMPUTE = [&](int buf){
    const unsigned short* Sb = S[buf];
    bf16x8 af[FM], bfr[FN];
    #pragma unroll
    for (int i=0;i<FM;i++) {
      const int r = wr*(BM/2) + i*16 + l15;
      af[i]  = *(const bf16x8*)&Sb[r*32 + ((lhi ^ (r&3))*8)];
    }
    #pragma unroll
    for (int j=0;j<FN;j++) {
      const int r = wc*(BN/2) + j*16 + l15;
      bfr[j] = *(const bf16x8*)&Sb[BM*32 + r*32 + ((lhi ^ (r&3))*8)];
    }
    #pragma unroll
    for (int i=0;i<FM;i++)
      #pragma unroll
      for (int j=0;j<FN;j++)
        acc[i][j] = __builtin_amdgcn_mfma_f32_16x16x32_bf16(af[i], bfr[j], acc[i][j], 0,0,0);
  };

  STAGE(0, 0);
  if (Kiters > 1) STAGE(1, 1);
  for (int kt=0; kt<Kiters; ++kt) {
    if (kt+1 < Kiters) waitcnt_vm<UNITS>();          // tile kt retired; kt+1 in flight
    else               waitcnt_vm<0>();              // last tile: full drain
    __builtin_amdgcn_s_barrier();                    // raw barrier: no auto-drain
    __builtin_amdgcn_sched_barrier(0);
    COMPUTE(kt%3);
    if (kt+2 < Kiters) STAGE(kt+2, (kt+2)%3);        // buf freed by barrier above
  }

  #pragma unroll
  for (int i=0;i<FM;i++) {
    #pragma unroll
    for (int j=0;j<FN;j++) {
      long col = bn + wc*(BN/2) + j*16 + l15;
      float bb = bias ? bias[col] : 0.f;
      #pragma unroll
      for (int q=0;q<4;q++) {
        long row = bm + wr*(BM/2) + i*16 + lhi*4 + q;
        float v = acc[i][j][q] + bb;
        long off = (long)blockIdx.z*sCb + row*ldc + col;
        if constexpr (OMODE==0 || OMODE==2) Cf[off] = v;
        if constexpr (OMODE==1 || OMODE==2) Cb[off] = f2b(v);
      }
    }
  }
}

// ---------------- top-16 + softmax weights per token ----------------
__global__ __launch_bounds__(256) void k_topk_softmax(const float* __restrict__ scores,
                                                      int* __restrict__ topidx,
                                                      float* __restrict__ topw)
{
  __shared__ float sv[2048];
  __shared__ float rv[256];
  __shared__ int   ri[256];
  __shared__ float selv[16];
  __shared__ int   seli[16];
  const int tid = threadIdx.x;
  const long t = blockIdx.x;
  const float* row = scores + t*2048;
  #pragma unroll
  for (int s=0;s<2;s++) ((float4*)sv)[tid + s*256] = ((const float4*)row)[tid + s*256];
  __syncthreads();
  for (int it=0; it<16; ++it) {
    float best = -1e30f; int bidx = 0x7FFFFFFF;
    #pragma unroll
    for (int s=0;s<8;s++) {
      int j = tid + s*256;
      float v = sv[j];
      if (v > best) { best = v; bidx = j; }   // ascending j: ties keep lowest idx
    }
    rv[tid]=best; ri[tid]=bidx;
    __syncthreads();
    if (tid < 64) {
      float bv = rv[tid]; int bi = ri[tid];
      #pragma unroll
      for (int s=1;s<4;s++) {
        float v2 = rv[tid+64*s]; int i2 = ri[tid+64*s];
        if (v2 > bv || (v2 == bv && i2 < bi)) { bv=v2; bi=i2; }
      }
      #pragma unroll
      for (int off=32; off; off>>=1) {
        float v2 = __shfl_xor(bv, off); int i2 = __shfl_xor(bi, off);
        if (v2 > bv || (v2 == bv && i2 < bi)) { bv=v2; bi=i2; }
      }
      if (tid == 0) { selv[it]=bv; seli[it]=bi; sv[bi] = -1e30f; }
    }
    __syncthreads();
  }
  if (tid == 0) {
    float m = selv[0], ssum = 0.f, w[16];
    #pragma unroll
    for (int k2=0;k2<16;k2++){ w[k2] = expf(selv[k2]-m); ssum += w[k2]; }
    float inv = 1.f/ssum;
    #pragma unroll
    for (int k2=0;k2<16;k2++){ topw[t*16+k2]=w[k2]*inv; topidx[t*16+k2]=seli[k2]; }
  }
}

// ---- gather + weighted combine + GELU, XCD-partitioned along d_ff ----
// chunk c = blockIdx.x & 7 (block i -> XCD i&7 round-robin): XCD c only ever
// touches firing[:, c*512 .. c*512+512) = 2 MB -> stays L2-resident per XCD.
// token group = blockIdx.x >> 3, 4 tokens per block (64 lanes each, 8 f/lane).
__global__ __launch_bounds__(256) void k_gather_gelu(const int* __restrict__ topidx,
                                                     const float* __restrict__ topw,
                                                     const unsigned short* __restrict__ firing,
                                                     unsigned short* __restrict__ gact)
{
  __shared__ int idx[4][16]; __shared__ float w[4][16];
  const int tid = threadIdx.x;
  const int c = blockIdx.x & 7;
  const long t0 = (long)(blockIdx.x >> 3) * 4;
  if (tid < 64) {
    int tok = tid >> 4, k = tid & 15;
    idx[tok][k] = topidx[(t0+tok)*16 + k];
    w[tok][k]   = topw[(t0+tok)*16 + k];
  }
  __syncthreads();
  const int tok = tid >> 6, lane = tid & 63;
  const int f0 = c*512 + lane*8;
  float acc[8] = {0,0,0,0,0,0,0,0};
  #pragma unroll
  for (int k=0;k<16;k++) {
    uint4 v = *(const uint4*)(firing + (long)idx[tok][k]*4096 + f0);
    const unsigned short* pu = (const unsigned short*)&v;
    float wk = w[tok][k];
    #pragma unroll
    for (int e=0;e<8;e++) acc[e] += wk * b2f(pu[e]);
  }
  float g[8];
  #pragma unroll
  for (int e=0;e<8;e++) g[e] = gelu_exact(acc[e]);
  uint4 ov;
  ov.x = pack2(g[0],g[1]); ov.y = pack2(g[2],g[3]);
  ov.z = pack2(g[4],g[5]); ov.w = pack2(g[6],g[7]);
  *(uint4*)(gact + (t0+tok)*4096 + f0) = ov;
}

// ---------------- V transpose per (b,h): vT[bh][d][t] = qkv[b,t][2048+h*64+d] --
__global__ __launch_bounds__(256) void k_vtrans(const unsigned short* __restrict__ qkv,
                                                unsigned short* __restrict__ vT)
{
  __shared__ unsigned short tile[64][65];
  int bh = blockIdx.y; int b = bh>>4, h = bh&15;
  long t0 = (long)blockIdx.x*64;
  const int tid = threadIdx.x;
  #pragma unroll
  for (int s=0;s<16;s++) {
    int i = tid + s*256;
    int r = i>>6, c = i&63;
    tile[r][c] = qkv[ (long)(b*1024 + t0 + r)*3072 + 2048 + h*64 + c ];
  }
  __syncthreads();
  #pragma unroll
  for (int s=0;s<16;s++) {
    int i = tid + s*256;
    int c = i>>6, r = i&63;
    vT[ (long)bh*65536 + (long)c*1024 + t0 + r ] = tile[r][c];
  }
}

// ------------- in-place row softmax (1/8 scale) over bf16 logits ----------------
__global__ __launch_bounds__(256) void k_softmax_row_bf16(unsigned short* __restrict__ logits)
{
  const long r = blockIdx.x;
  const int tid = threadIdx.x;
  const int wave = tid>>6, lane = tid&63;
  unsigned short* row = logits + r*1024;
  ushort4 u = ((const ushort4*)row)[tid];
  float v0 = b2f(u.x)*0.125f, v1 = b2f(u.y)*0.125f,
        v2 = b2f(u.z)*0.125f, v3 = b2f(u.w)*0.125f;
  float m = fmaxf(fmaxf(v0,v1),fmaxf(v2,v3));
  #pragma unroll
  for (int off=32; off; off>>=1) m = fmaxf(m, __shfl_xor(m, off));
  __shared__ float wm[4], wsum[4];
  if (lane==0) wm[wave]=m;
  __syncthreads();
  m = fmaxf(fmaxf(wm[0],wm[1]),fmaxf(wm[2],wm[3]));
  float e0=expf(v0-m), e1=expf(v1-m), e2=expf(v2-m), e3=expf(v3-m);
  float s = e0+e1+e2+e3;
  #pragma unroll
  for (int off=32; off; off>>=1) s += __shfl_xor(s, off);
  if (lane==0) wsum[wave]=s;
  __syncthreads();
  s = wsum[0]+wsum[1]+wsum[2]+wsum[3];
  float inv = 1.f/s;
  ushort4 o; o.x=f2b(e0*inv); o.y=f2b(e1*inv); o.z=f2b(e2*inv); o.w=f2b(e3*inv);
  ((ushort4*)row)[tid] = o;
}

// ---------------- residual + LayerNorm (row = 1024) ----------------
__global__ __launch_bounds__(256) void k_ln_res(const float* __restrict__ a,
                                                const float* b,          // may alias out
                                                const float* __restrict__ g,
                                                const float* __restrict__ be,
                                                float* out)
{
  const long t = blockIdx.x;
  const int tid = threadIdx.x;
  const int wave = tid>>6, lane = tid&63;
  float4 av = ((const float4*)(a + t*1024))[tid];
  float4 bv = ((const float4*)(b + t*1024))[tid];
  float4 sv = {av.x+bv.x, av.y+bv.y, av.z+bv.z, av.w+bv.w};
  float sum = sv.x+sv.y+sv.z+sv.w;
  float sq  = sv.x*sv.x + sv.y*sv.y + sv.z*sv.z + sv.w*sv.w;
  #pragma unroll
  for (int off=32; off; off>>=1){ sum += __shfl_xor(sum,off); sq += __shfl_xor(sq,off); }
  __shared__ float s1[4], s2[4];
  if (lane==0){ s1[wave]=sum; s2[wave]=sq; }
  __syncthreads();
  sum = s1[0]+s1[1]+s1[2]+s1[3];
  sq  = s2[0]+s2[1]+s2[2]+s2[3];
  float mu  = sum * (1.f/1024.f);
  float var = sq * (1.f/1024.f) - mu*mu;
  float rs  = rsqrtf(var + 1e-5f);
  float4 gv  = ((const float4*)g)[tid];
  float4 bev = ((const float4*)be)[tid];
  float4 ov = { (sv.x-mu)*rs*gv.x + bev.x,
                (sv.y-mu)*rs*gv.y + bev.y,
                (sv.z-mu)*rs*gv.z + bev.z,
                (sv.w-mu)*rs*gv.w + bev.w };
  ((float4*)(out + t*1024))[tid] = ov;
}

// =====================================================================
extern "C" void kernel_launch(void* const* d_in, const int* in_sizes, int n_in,
                              void* d_out, int out_size, void* d_ws, size_t ws_size,
                              hipStream_t stream)
{
  const float* x        = (const float*)d_in[0];
  const float* w_router = (const float*)d_in[1];
  const float* b_router = (const float*)d_in[2];
  const float* firing   = (const float*)d_in[3];
  const float* w_pool   = (const float*)d_in[4];
  const float* b_pool   = (const float*)d_in[5];
  const float* w_in     = (const float*)d_in[6];
  const float* b_in     = (const float*)d_in[7];
  const float* w_ao     = (const float*)d_in[8];
  const float* b_ao     = (const float*)d_in[9];
  const float* g1       = (const float*)d_in[10];
  const float* be1      = (const float*)d_in[11];
  const float* g2       = (const float*)d_in[12];
  const float* be2      = (const float*)d_in[13];
  float* out = (float*)d_out;
  char* ws = (char*)d_ws;

  // ws layout (bytes); P is triple-aliased: scores(f32,32MB) -> gact(bf16,32MB)
  // -> per-batch logits/probs(bf16,32MB). Total 164,102,144 B.
  unsigned short* xb    = (unsigned short*)(ws + 0);          //  8,388,608
  unsigned short* wrT   = (unsigned short*)(ws + 8388608);    //  4,194,304
  unsigned short* firb  = (unsigned short*)(ws + 12582912);   // 16,777,216
  unsigned short* wpoT  = (unsigned short*)(ws + 29360128);   //  8,388,608
  unsigned short* winT  = (unsigned short*)(ws + 37748736);   //  6,291,456
  unsigned short* waoT  = (unsigned short*)(ws + 44040192);   //  2,097,152
  float*  scores        = (float*)(ws + 46137344);            // 33,554,432 (P)
  unsigned short* gact  = (unsigned short*)(ws + 46137344);   // alias P
  unsigned short* lgts  = (unsigned short*)(ws + 46137344);   // alias P (per-batch)
  int*    topi          = (int*)(ws + 79691776);              //    262,144
  float*  topw          = (float*)(ws + 79953920);            //    262,144
  float*  neuf          = (float*)(ws + 80216064);            // 16,777,216
  unsigned short* neub  = (unsigned short*)(ws + 96993280);   //  8,388,608
  unsigned short* qkvb  = (unsigned short*)(ws + 105381888);  // 25,165,824
  unsigned short* vT    = (unsigned short*)(ws + 130547712);  //  8,388,608
  unsigned short* ctx   = (unsigned short*)(ws + 138936320);  //  8,388,608
  float*  attn          = (float*)(ws + 147324928);           // 16,777,216

  if (ws_size < 164102144u) return; // insufficient scratch: fail loudly

  // ---- prep: bf16 casts + transposed bf16 weights ----
  k_cast_bf16<<<4096, 256, 0, stream>>>(x, xb, 4096L*1024/4);
  k_cast_bf16<<<8192, 256, 0, stream>>>(firing, firb, 2048L*4096/4);
  k_transpose_cast<<<dim3(2048/32, 1024/32), 256, 0, stream>>>(w_router, wrT, 1024, 2048);
  k_transpose_cast<<<dim3(1024/32, 4096/32), 256, 0, stream>>>(w_pool,   wpoT, 4096, 1024);
  k_transpose_cast<<<dim3(3072/32, 1024/32), 256, 0, stream>>>(w_in,     winT, 1024, 3072);
  k_transpose_cast<<<dim3(1024/32, 1024/32), 256, 0, stream>>>(w_ao,     waoT, 1024, 1024);

  // ---- router: scores = x @ w_router + b_router (128x128 tiles, 512 wg) ----
  k_gemm_bt<4,4,0><<<dim3(16,32,1),256,0,stream>>>(xb,1024,0, wrT,1024,0,
        scores,nullptr,2048,0, b_router, 32);
  k_topk_softmax<<<4096,256,0,stream>>>(scores, topi, topw);
  k_gather_gelu<<<8192,256,0,stream>>>(topi, topw, firb, gact);

  // ---- pool: neuron_out = gelu(combined) @ w_pool_out + b_pool (128x64, 512 wg) ----
  k_gemm_bt<4,2,2><<<dim3(16,32,1),256,0,stream>>>(gact,4096,0, wpoT,4096,0,
        neuf,neub,1024,0, b_pool, 128);

  // ---- qkv = neuron_out @ w_in + b_in (bf16; 128x128, 768 wg) ----
  k_gemm_bt<4,4,1><<<dim3(24,32,1),256,0,stream>>>(neub,1024,0, winT,1024,0,
        nullptr,qkvb,3072,0, b_in, 32);

  k_vtrans<<<dim3(16,64),256,0,stream>>>(qkvb, vT);

  // ---- attention: 4 per-batch chunks of 16 heads, z = head ----
  for (int b=0;b<4;b++) {
    const unsigned short* qbase = qkvb + (long)b*3145728;
    const unsigned short* kbase = qkvb + (long)b*3145728 + 1024;
    // logits[h][t][t'] bf16 (scaled later in softmax)
    k_gemm_bt<4,4,1><<<dim3(8,8,16),256,0,stream>>>(qbase,3072,64, kbase,3072,64,
          nullptr,lgts,1024,1048576, nullptr, 2);
    k_softmax_row_bf16<<<16384,256,0,stream>>>(lgts);
    const unsigned short* vbase = vT + (long)b*16*65536;
    unsigned short* cbase = ctx + (long)b*1048576;
    // PV: 64x64 tiles -> 256 wg per batch
    k_gemm_bt<2,2,1><<<dim3(1,16,16),256,0,stream>>>(lgts,1024,1048576, vbase,1024,65536,
          nullptr,cbase,1024,64, nullptr, 32);
  }

  // ---- attn_out = ctx @ w_attn_out + b_ao (128x64, 512 wg) ----
  k_gemm_bt<4,2,0><<<dim3(16,32,1),256,0,stream>>>(ctx,1024,0, waoT,1024,0,
        attn,nullptr,1024,0, b_ao, 32);

  // ---- h = LN(x + attn) (in-place into attn); out = LN(h + neuron_out) ----
  k_ln_res<<<4096,256,0,stream>>>(x, attn, g1, be1, attn);
  k_ln_res<<<4096,256,0,stream>>>(attn, neuf, g2, be2, out);
}

// Round 5
// 307.106 us; speedup vs baseline: 2.8224x; 1.4724x over previous
//
#include <hip/hip_runtime.h>
#include <math.h>

typedef __attribute__((ext_vector_type(8))) __bf16 bf16x8;
typedef __attribute__((ext_vector_type(4))) __bf16 bf16x4;
typedef __attribute__((ext_vector_type(4))) float f32x4;

#define DEV static __device__ __forceinline__

DEV float b2f(unsigned short u){ union{unsigned i; float f;} c; c.i=((unsigned)u)<<16; return c.f; }
DEV unsigned short f2b(float f){
  union{float f; unsigned u;} c; c.f=f;
  unsigned r = 0x7FFFu + ((c.u>>16)&1u);
  return (unsigned short)((c.u + r)>>16);
}
DEV unsigned pack2(float a, float b){ return (unsigned)f2b(a) | ((unsigned)f2b(b)<<16); }
DEV float gelu_exact(float x){ return 0.5f*x*(1.f+erff(x*0.70710678118654752f)); }

typedef __attribute__((address_space(1))) void gas_void;
typedef __attribute__((address_space(3))) void las_void;
DEV void gload_lds16(const unsigned short* g, unsigned short* l){
  __builtin_amdgcn_global_load_lds((const gas_void*)g, (las_void*)l, 16, 0, 0);
}

template<int N> DEV void waitcnt_vm(){
  if constexpr(N==0) asm volatile("s_waitcnt vmcnt(0)" ::: "memory");
  else if constexpr(N==2) asm volatile("s_waitcnt vmcnt(2)" ::: "memory");
  else if constexpr(N==3) asm volatile("s_waitcnt vmcnt(3)" ::: "memory");
  else if constexpr(N==4) asm volatile("s_waitcnt vmcnt(4)" ::: "memory");
  else                    asm volatile("s_waitcnt vmcnt(0)" ::: "memory");
}

// ---------------- elementwise cast fp32 -> bf16 (vectorized x4) ----------------
__global__ __launch_bounds__(256) void k_cast_bf16(const float* __restrict__ in,
                                                   unsigned short* __restrict__ out, long n4)
{
  long i = (long)blockIdx.x*256 + threadIdx.x;
  if (i >= n4) return;
  float4 v = ((const float4*)in)[i];
  ushort4 o; o.x=f2b(v.x); o.y=f2b(v.y); o.z=f2b(v.z); o.w=f2b(v.w);
  ((ushort4*)out)[i] = o;
}

// ---------------- transpose + cast: out[c][r] = bf16(in[r][c]) ----------------
__global__ __launch_bounds__(256) void k_transpose_cast(const float* __restrict__ in,
                                                        unsigned short* __restrict__ out,
                                                        int R, int C)
{
  __shared__ float tile[32][33];
  int tc = blockIdx.x*32, tr = blockIdx.y*32;
  int lx = threadIdx.x & 31, ly = threadIdx.x >> 5;
  #pragma unroll
  for (int s=0;s<4;s++) tile[ly+s*8][lx] = in[(long)(tr+ly+s*8)*C + tc+lx];
  __syncthreads();
  #pragma unroll
  for (int s=0;s<4;s++) out[(long)(tc+ly+s*8)*R + tr+lx] = f2b(tile[lx][ly+s*8]);
}

// -- 3-buffer counted-vmcnt bf16 MFMA GEMM (T3-min + T4), B transposed Bt[n][k] --
template<int FM, int FN, int OMODE>
__global__ __launch_bounds__(256) void k_gemm_bt(
  const unsigned short* __restrict__ A, long lda, long sAb,
  const unsigned short* __restrict__ Bt, long ldb, long sBb,
  float* __restrict__ Cf, unsigned short* __restrict__ Cb, long ldc, long sCb,
  const float* __restrict__ bias, int Kiters)
{
  constexpr int BM = 32*FM, BN = 32*FN;
  constexpr int AR16 = BM/16, TOT16 = (BM+BN)/16;   // 16-row stage units
  constexpr int UNITS = TOT16/4;                    // gload_lds per wave per tile
  static_assert(TOT16 % 4 == 0, "stage units must split across 4 waves");
  __shared__ __align__(16) unsigned short S[3][TOT16*512];
  const int tid = threadIdx.x;
  const int wave = tid>>6, lane = tid&63;
  const int wr = wave>>1, wc = wave&1;
  const int l15 = lane&15, lhi = lane>>4;
  const int lrow = lane>>2;
  const int lcol = ((lane&3) ^ (lrow&3))*8;         // T2 pre-swizzled source slot

  // XCD-aware bijective swizzle within the z-slice
  const int gx = gridDim.x;
  const int nwg = gx*gridDim.y;
  const int id = blockIdx.y*gx + blockIdx.x;
  const int sid = (id&7)*(nwg>>3) + (id>>3);
  const long bm = (long)(sid / gx)*BM, bn = (long)(sid % gx)*BN;

  const unsigned short* Ab  = A  + (long)blockIdx.z*sAb + bm*lda;
  const unsigned short* Btb = Bt + (long)blockIdx.z*sBb + bn*ldb;

  f32x4 acc[FM][FN];
  #pragma unroll
  for (int i=0;i<FM;i++)
    #pragma unroll
    for (int j=0;j<FN;j++) acc[i][j] = (f32x4){0.f,0.f,0.f,0.f};

  auto STAGE = [&](int kt, int buf){
    const long k0 = (long)kt*32;
    #pragma unroll
    for (int u=0; u<UNITS; ++u) {
      const int t = wave + u*4;                      // wave-uniform stage unit
      const unsigned short* g;
      if (t < AR16) g = Ab  + (long)(t*16 + lrow)*lda + k0 + lcol;
      else          g = Btb + (long)((t-AR16)*16 + lrow)*ldb + k0 + lcol;
      gload_lds16(g, &S[buf][t*512]);                // linear dest, swz source
    }
  };
  auto COMPUTE = [&](int buf){
    const unsigned short* Sb = S[buf];
    bf16x8 af[FM], bfr[FN];
    #pragma unroll
    for (int i=0;i<FM;i++) {
      const int r = wr*(BM/2) + i*16 + l15;
      af[i]  = *(const bf16x8*)&Sb[r*32 + ((lhi ^ (r&3))*8)];
    }
    #pragma unroll
    for (int j=0;j<FN;j++) {
      const int r = wc*(BN/2) + j*16 + l15;
      bfr[j] = *(const bf16x8*)&Sb[BM*32 + r*32 + ((lhi ^ (r&3))*8)];
    }
    #pragma unroll
    for (int i=0;i<FM;i++)
      #pragma unroll
      for (int j=0;j<FN;j++)
        acc[i][j] = __builtin_amdgcn_mfma_f32_16x16x32_bf16(af[i], bfr[j], acc[i][j], 0,0,0);
  };

  STAGE(0, 0);
  if (Kiters > 1) STAGE(1, 1);
  for (int kt=0; kt<Kiters; ++kt) {
    if (kt+1 < Kiters) waitcnt_vm<UNITS>();          // tile kt retired; kt+1 in flight
    else               waitcnt_vm<0>();              // last tile: full drain
    __builtin_amdgcn_s_barrier();                    // raw barrier: no auto-drain
    __builtin_amdgcn_sched_barrier(0);
    COMPUTE(kt%3);
    if (kt+2 < Kiters) STAGE(kt+2, (kt+2)%3);        // buf freed by barrier above
  }

  #pragma unroll
  for (int i=0;i<FM;i++) {
    #pragma unroll
    for (int j=0;j<FN;j++) {
      long col = bn + wc*(BN/2) + j*16 + l15;
      float bb = bias ? bias[col] : 0.f;
      #pragma unroll
      for (int q=0;q<4;q++) {
        long row = bm + wr*(BM/2) + i*16 + lhi*4 + q;
        float v = acc[i][j][q] + bb;
        long off = (long)blockIdx.z*sCb + row*ldc + col;
        if constexpr (OMODE==0 || OMODE==2) Cf[off] = v;
        if constexpr (OMODE==1 || OMODE==2) Cb[off] = f2b(v);
      }
    }
  }
}

// ---------------- top-16 + softmax weights per token ----------------
__global__ __launch_bounds__(256) void k_topk_softmax(const float* __restrict__ scores,
                                                      int* __restrict__ topidx,
                                                      float* __restrict__ topw)
{
  __shared__ float sv[2048];
  __shared__ float rv[256];
  __shared__ int   ri[256];
  __shared__ float selv[16];
  __shared__ int   seli[16];
  const int tid = threadIdx.x;
  const long t = blockIdx.x;
  const float* row = scores + t*2048;
  #pragma unroll
  for (int s=0;s<2;s++) ((float4*)sv)[tid + s*256] = ((const float4*)row)[tid + s*256];
  __syncthreads();
  for (int it=0; it<16; ++it) {
    float best = -1e30f; int bidx = 0x7FFFFFFF;
    #pragma unroll
    for (int s=0;s<8;s++) {
      int j = tid + s*256;
      float v = sv[j];
      if (v > best) { best = v; bidx = j; }   // ascending j: ties keep lowest idx
    }
    rv[tid]=best; ri[tid]=bidx;
    __syncthreads();
    if (tid < 64) {
      float bv = rv[tid]; int bi = ri[tid];
      #pragma unroll
      for (int s=1;s<4;s++) {
        float v2 = rv[tid+64*s]; int i2 = ri[tid+64*s];
        if (v2 > bv || (v2 == bv && i2 < bi)) { bv=v2; bi=i2; }
      }
      #pragma unroll
      for (int off=32; off; off>>=1) {
        float v2 = __shfl_xor(bv, off); int i2 = __shfl_xor(bi, off);
        if (v2 > bv || (v2 == bv && i2 < bi)) { bv=v2; bi=i2; }
      }
      if (tid == 0) { selv[it]=bv; seli[it]=bi; sv[bi] = -1e30f; }
    }
    __syncthreads();
  }
  if (tid == 0) {
    float m = selv[0], ssum = 0.f, w[16];
    #pragma unroll
    for (int k2=0;k2<16;k2++){ w[k2] = expf(selv[k2]-m); ssum += w[k2]; }
    float inv = 1.f/ssum;
    #pragma unroll
    for (int k2=0;k2<16;k2++){ topw[t*16+k2]=w[k2]*inv; topidx[t*16+k2]=seli[k2]; }
  }
}

// ---- gather + weighted combine + GELU, XCD-partitioned along d_ff ----
__global__ __launch_bounds__(256) void k_gather_gelu(const int* __restrict__ topidx,
                                                     const float* __restrict__ topw,
                                                     const unsigned short* __restrict__ firing,
                                                     unsigned short* __restrict__ gact)
{
  __shared__ int idx[4][16]; __shared__ float w[4][16];
  const int tid = threadIdx.x;
  const int c = blockIdx.x & 7;
  const long t0 = (long)(blockIdx.x >> 3) * 4;
  if (tid < 64) {
    int tok = tid >> 4, k = tid & 15;
    idx[tok][k] = topidx[(t0+tok)*16 + k];
    w[tok][k]   = topw[(t0+tok)*16 + k];
  }
  __syncthreads();
  const int tok = tid >> 6, lane = tid & 63;
  const int f0 = c*512 + lane*8;
  float acc[8] = {0,0,0,0,0,0,0,0};
  #pragma unroll
  for (int k=0;k<16;k++) {
    uint4 v = *(const uint4*)(firing + (long)idx[tok][k]*4096 + f0);
    const unsigned short* pu = (const unsigned short*)&v;
    float wk = w[tok][k];
    #pragma unroll
    for (int e=0;e<8;e++) acc[e] += wk * b2f(pu[e]);
  }
  float g[8];
  #pragma unroll
  for (int e=0;e<8;e++) g[e] = gelu_exact(acc[e]);
  uint4 ov;
  ov.x = pack2(g[0],g[1]); ov.y = pack2(g[2],g[3]);
  ov.z = pack2(g[4],g[5]); ov.w = pack2(g[6],g[7]);
  *(uint4*)(gact + (t0+tok)*4096 + f0) = ov;
}

// ---------------- V transpose per (b,h): vT[bh][d][t] = qkv[b,t][2048+h*64+d] --
__global__ __launch_bounds__(256) void k_vtrans(const unsigned short* __restrict__ qkv,
                                                unsigned short* __restrict__ vT)
{
  __shared__ unsigned short tile[64][65];
  int bh = blockIdx.y; int b = bh>>4, h = bh&15;
  long t0 = (long)blockIdx.x*64;
  const int tid = threadIdx.x;
  #pragma unroll
  for (int s=0;s<16;s++) {
    int i = tid + s*256;
    int r = i>>6, c = i&63;
    tile[r][c] = qkv[ (long)(b*1024 + t0 + r)*3072 + 2048 + h*64 + c ];
  }
  __syncthreads();
  #pragma unroll
  for (int s=0;s<16;s++) {
    int i = tid + s*256;
    int c = i>>6, r = i&63;
    vT[ (long)bh*65536 + (long)c*1024 + t0 + r ] = tile[r][c];
  }
}

// ---------------- fused flash attention ----------------
// grid = (8 q-tiles, 64 b*h); block = 256 (4 waves). Per block: Q-tile 128 rows,
// loop 8 KV tiles of 128. Swapped QK^T (mfma(K,Q) -> S^T): lane owns softmax
// rows q = jq*16 + l15 -> row stats in-lane + shfl_xor(16|32). P stays in
// registers: pa[jq][kk] is a pure repack of S^T accs; V^T fragments are read at
// the matching permuted k-order (both operands use the same (lhi,e)->k map).
// K/V double-buffered LDS, XOR-swizzled via pre-swizzled global source.
__global__ __launch_bounds__(256) void k_flash_attn(
  const unsigned short* __restrict__ qkv,   // [4][1024][3072]
  const unsigned short* __restrict__ vT,    // [64 bh][64 d][1024 t]
  unsigned short* __restrict__ ctx)         // [4][1024][1024]
{
  __shared__ __align__(16) unsigned short Qs[128*64];
  __shared__ __align__(16) unsigned short Ks[2][128*64];
  __shared__ __align__(16) unsigned short Vs[2][64*128];
  const int tid = threadIdx.x;
  const int wave = tid>>6, lane = tid&63;
  const int l15 = lane&15, lhi = lane>>4;
  const int bh = blockIdx.y, b = bh>>4, h = bh&15;
  const long q0 = (long)blockIdx.x*128;
  const unsigned short* Qg = qkv + ((long)b*1024 + q0)*3072 + h*64;
  const unsigned short* Kg = qkv + (long)b*1024*3072 + 1024 + h*64;
  const unsigned short* Vg = vT + (long)bh*65536;

  // stage Q once: 16 units of 8 rows x 64 cols; source chunk pre-XOR'd by row
  {
    const int sr = lane>>3, sc = (lane&7)^sr;
    #pragma unroll
    for (int uu=0; uu<4; ++uu){
      int u = wave + uu*4;
      gload_lds16(Qg + (long)(u*8+sr)*3072 + sc*8, &Qs[u*512]);
    }
  }
  auto STAGE_KV = [&](int t, int s){
    const long kv0 = (long)t*128;
    const int sr = lane>>3, sc = (lane&7)^sr;
    #pragma unroll
    for (int uu=0; uu<4; ++uu){
      int u = wave + uu*4;
      gload_lds16(Kg + (kv0 + u*8 + sr)*3072 + sc*8, &Ks[s][u*512]);
    }
    const int vc = (lane&15) ^ ((wave&1)*4 + lhi);   // row = u*4+lhi, r&7 = (u&1)*4+lhi
    #pragma unroll
    for (int uu=0; uu<4; ++uu){
      int u = wave + uu*4;
      gload_lds16(Vg + (long)(u*4+lhi)*1024 + kv0 + vc*8, &Vs[s][u*512]);
    }
  };

  STAGE_KV(0, 0);
  __syncthreads();

  // hoist Q fragments: qf[jq][ks], rows wave*32 + jq*16 + l15
  bf16x8 qf[2][2];
  #pragma unroll
  for (int jq=0;jq<2;jq++){
    const int r = wave*32 + jq*16 + l15;
    #pragma unroll
    for (int ks=0;ks<2;ks++)
      qf[jq][ks] = *(const bf16x8*)&Qs[r*64 + (((ks*4+lhi)^(r&7))*8)];
  }

  f32x4 acco[2][4];
  #pragma unroll
  for (int mi=0;mi<2;mi++)
    #pragma unroll
    for (int nf=0;nf<4;nf++) acco[mi][nf] = (f32x4){0.f,0.f,0.f,0.f};
  float m_run[2] = {-1e30f,-1e30f}, l_run[2] = {0.f,0.f};

  int sel = 0;
  for (int t=0; t<8; ++t) {
    if (t < 7) STAGE_KV(t+1, sel^1);
    // ---- S^T = K-tile @ Q^T : accs[fk][jq], rows k = fk*16+lhi*4+reg, col q=l15
    f32x4 accs[8][2];
    #pragma unroll
    for (int fk=0;fk<8;fk++){
      accs[fk][0] = (f32x4){0.f,0.f,0.f,0.f};
      accs[fk][1] = (f32x4){0.f,0.f,0.f,0.f};
      const int r = fk*16 + l15;
      bf16x8 k0 = *(const bf16x8*)&Ks[sel][r*64 + ((lhi^(r&7))*8)];
      accs[fk][0] = __builtin_amdgcn_mfma_f32_16x16x32_bf16(k0, qf[0][0], accs[fk][0],0,0,0);
      accs[fk][1] = __builtin_amdgcn_mfma_f32_16x16x32_bf16(k0, qf[1][0], accs[fk][1],0,0,0);
      bf16x8 k1 = *(const bf16x8*)&Ks[sel][r*64 + (((4+lhi)^(r&7))*8)];
      accs[fk][0] = __builtin_amdgcn_mfma_f32_16x16x32_bf16(k1, qf[0][1], accs[fk][0],0,0,0);
      accs[fk][1] = __builtin_amdgcn_mfma_f32_16x16x32_bf16(k1, qf[1][1], accs[fk][1],0,0,0);
    }
    // ---- online softmax (rows q = jq*16+l15 are lane-local) + pack P to regs
    bf16x8 pa[2][4];
    float fsc[2];
    #pragma unroll
    for (int jq=0;jq<2;jq++){
      float mt = -1e30f;
      #pragma unroll
      for (int fk=0;fk<8;fk++)
        #pragma unroll
        for (int q=0;q<4;q++) mt = fmaxf(mt, accs[fk][jq][q]);
      mt = fmaxf(mt, __shfl_xor(mt,16));
      mt = fmaxf(mt, __shfl_xor(mt,32));
      mt *= 0.125f;
      float mnew = fmaxf(m_run[jq], mt);
      float fj = __expf(m_run[jq] - mnew);
      float ssum = 0.f;
      #pragma unroll
      for (int fk=0;fk<8;fk++)
        #pragma unroll
        for (int q=0;q<4;q++){
          float p = __expf(accs[fk][jq][q]*0.125f - mnew);
          ssum += p;
          pa[jq][fk>>1][(fk&1)*4+q] = (__bf16)p;   // k = (fk>>1)*32 + (fk&1)*16 + lhi*4 + q
        }
      ssum += __shfl_xor(ssum,16);
      ssum += __shfl_xor(ssum,32);
      l_run[jq] = l_run[jq]*fj + ssum;
      m_run[jq] = mnew;
      fsc[jq] = fj;
    }
    // ---- rescale O (O rows are lhi-owned: broadcast factor from l15-owner lane)
    #pragma unroll
    for (int mi=0;mi<2;mi++)
      #pragma unroll
      for (int q=0;q<4;q++){
        float fr = __shfl(fsc[mi], (lane&48)|(lhi*4+q));
        #pragma unroll
        for (int nf=0;nf<4;nf++) acco[mi][nf][q] *= fr;
      }
    // ---- O += P @ V : B-operand V^T read at the permuted k-order
    #pragma unroll
    for (int kk=0;kk<4;kk++)
      #pragma unroll
      for (int nf=0;nf<4;nf++){
        const int rv = nf*16 + l15;
        const int cb = kk*4 + (lhi>>1);
        bf16x4 v0 = *(const bf16x4*)&Vs[sel][rv*128 + (( cb   ^(l15&7))*8) + (lhi&1)*4];
        bf16x4 v1 = *(const bf16x4*)&Vs[sel][rv*128 + (((cb+2)^(l15&7))*8) + (lhi&1)*4];
        bf16x8 vb = __builtin_shufflevector(v0, v1, 0,1,2,3,4,5,6,7);
        acco[0][nf] = __builtin_amdgcn_mfma_f32_16x16x32_bf16(pa[0][kk], vb, acco[0][nf],0,0,0);
        acco[1][nf] = __builtin_amdgcn_mfma_f32_16x16x32_bf16(pa[1][kk], vb, acco[1][nf],0,0,0);
      }
    __syncthreads();    // drains vmcnt: tile t+1 resident; buffers safe to swap
    sel ^= 1;
  }

  // ---- finalize: divide by l (broadcast per O-row), store ctx
  #pragma unroll
  for (int mi=0;mi<2;mi++)
    #pragma unroll
    for (int q=0;q<4;q++){
      float lr = __shfl(l_run[mi], (lane&48)|(lhi*4+q));
      float inv = 1.f/lr;
      long row = q0 + wave*32 + mi*16 + lhi*4 + q;
      #pragma unroll
      for (int nf=0;nf<4;nf++)
        ctx[((long)b*1024 + row)*1024 + h*64 + nf*16 + l15] = f2b(acco[mi][nf][q]*inv);
    }
}

// ---------------- residual + LayerNorm (row = 1024) ----------------
__global__ __launch_bounds__(256) void k_ln_res(const float* __restrict__ a,
                                                const float* b,          // may alias out
                                                const float* __restrict__ g,
                                                const float* __restrict__ be,
                                                float* out)
{
  const long t = blockIdx.x;
  const int tid = threadIdx.x;
  const int wave = tid>>6, lane = tid&63;
  float4 av = ((const float4*)(a + t*1024))[tid];
  float4 bv = ((const float4*)(b + t*1024))[tid];
  float4 sv = {av.x+bv.x, av.y+bv.y, av.z+bv.z, av.w+bv.w};
  float sum = sv.x+sv.y+sv.z+sv.w;
  float sq  = sv.x*sv.x + sv.y*sv.y + sv.z*sv.z + sv.w*sv.w;
  #pragma unroll
  for (int off=32; off; off>>=1){ sum += __shfl_xor(sum,off); sq += __shfl_xor(sq,off); }
  __shared__ float s1[4], s2[4];
  if (lane==0){ s1[wave]=sum; s2[wave]=sq; }
  __syncthreads();
  sum = s1[0]+s1[1]+s1[2]+s1[3];
  sq  = s2[0]+s2[1]+s2[2]+s2[3];
  float mu  = sum * (1.f/1024.f);
  float var = sq * (1.f/1024.f) - mu*mu;
  float rs  = rsqrtf(var + 1e-5f);
  float4 gv  = ((const float4*)g)[tid];
  float4 bev = ((const float4*)be)[tid];
  float4 ov = { (sv.x-mu)*rs*gv.x + bev.x,
                (sv.y-mu)*rs*gv.y + bev.y,
                (sv.z-mu)*rs*gv.z + bev.z,
                (sv.w-mu)*rs*gv.w + bev.w };
  ((float4*)(out + t*1024))[tid] = ov;
}

// =====================================================================
extern "C" void kernel_launch(void* const* d_in, const int* in_sizes, int n_in,
                              void* d_out, int out_size, void* d_ws, size_t ws_size,
                              hipStream_t stream)
{
  const float* x        = (const float*)d_in[0];
  const float* w_router = (const float*)d_in[1];
  const float* b_router = (const float*)d_in[2];
  const float* firing   = (const float*)d_in[3];
  const float* w_pool   = (const float*)d_in[4];
  const float* b_pool   = (const float*)d_in[5];
  const float* w_in     = (const float*)d_in[6];
  const float* b_in     = (const float*)d_in[7];
  const float* w_ao     = (const float*)d_in[8];
  const float* b_ao     = (const float*)d_in[9];
  const float* g1       = (const float*)d_in[10];
  const float* be1      = (const float*)d_in[11];
  const float* g2       = (const float*)d_in[12];
  const float* be2      = (const float*)d_in[13];
  float* out = (float*)d_out;
  char* ws = (char*)d_ws;

  // ws layout (bytes); P region is aliased: scores(f32,32MB) -> gact(bf16,32MB).
  unsigned short* xb    = (unsigned short*)(ws + 0);          //  8,388,608
  unsigned short* wrT   = (unsigned short*)(ws + 8388608);    //  4,194,304
  unsigned short* firb  = (unsigned short*)(ws + 12582912);   // 16,777,216
  unsigned short* wpoT  = (unsigned short*)(ws + 29360128);   //  8,388,608
  unsigned short* winT  = (unsigned short*)(ws + 37748736);   //  6,291,456
  unsigned short* waoT  = (unsigned short*)(ws + 44040192);   //  2,097,152
  float*  scores        = (float*)(ws + 46137344);            // 33,554,432 (P)
  unsigned short* gact  = (unsigned short*)(ws + 46137344);   // alias P
  int*    topi          = (int*)(ws + 79691776);              //    262,144
  float*  topw          = (float*)(ws + 79953920);            //    262,144
  float*  neuf          = (float*)(ws + 80216064);            // 16,777,216
  unsigned short* neub  = (unsigned short*)(ws + 96993280);   //  8,388,608
  unsigned short* qkvb  = (unsigned short*)(ws + 105381888);  // 25,165,824
  unsigned short* vT    = (unsigned short*)(ws + 130547712);  //  8,388,608
  unsigned short* ctx   = (unsigned short*)(ws + 138936320);  //  8,388,608
  float*  attn          = (float*)(ws + 147324928);           // 16,777,216

  if (ws_size < 164102144u) return; // insufficient scratch: fail loudly

  // ---- prep: bf16 casts + transposed bf16 weights ----
  k_cast_bf16<<<4096, 256, 0, stream>>>(x, xb, 4096L*1024/4);
  k_cast_bf16<<<8192, 256, 0, stream>>>(firing, firb, 2048L*4096/4);
  k_transpose_cast<<<dim3(2048/32, 1024/32), 256, 0, stream>>>(w_router, wrT, 1024, 2048);
  k_transpose_cast<<<dim3(1024/32, 4096/32), 256, 0, stream>>>(w_pool,   wpoT, 4096, 1024);
  k_transpose_cast<<<dim3(3072/32, 1024/32), 256, 0, stream>>>(w_in,     winT, 1024, 3072);
  k_transpose_cast<<<dim3(1024/32, 1024/32), 256, 0, stream>>>(w_ao,     waoT, 1024, 1024);

  // ---- router: scores = x @ w_router + b_router (128x128 tiles, 512 wg) ----
  k_gemm_bt<4,4,0><<<dim3(16,32,1),256,0,stream>>>(xb,1024,0, wrT,1024,0,
        scores,nullptr,2048,0, b_router, 32);
  k_topk_softmax<<<4096,256,0,stream>>>(scores, topi, topw);
  k_gather_gelu<<<8192,256,0,stream>>>(topi, topw, firb, gact);

  // ---- pool: neuron_out = gelu(combined) @ w_pool_out + b_pool (128x64, 512 wg) ----
  k_gemm_bt<4,2,2><<<dim3(16,32,1),256,0,stream>>>(gact,4096,0, wpoT,4096,0,
        neuf,neub,1024,0, b_pool, 128);

  // ---- qkv = neuron_out @ w_in + b_in (bf16; 128x128, 768 wg) ----
  k_gemm_bt<4,4,1><<<dim3(24,32,1),256,0,stream>>>(neub,1024,0, winT,1024,0,
        nullptr,qkvb,3072,0, b_in, 32);

  // ---- attention: V transpose + fused flash (no logits materialization) ----
  k_vtrans<<<dim3(16,64),256,0,stream>>>(qkvb, vT);
  k_flash_attn<<<dim3(8,64),256,0,stream>>>(qkvb, vT, ctx);

  // ---- attn_out = ctx @ w_attn_out + b_ao (128x64, 512 wg) ----
  k_gemm_bt<4,2,0><<<dim3(16,32,1),256,0,stream>>>(ctx,1024,0, waoT,1024,0,
        attn,nullptr,1024,0, b_ao, 32);

  // ---- h = LN(x + attn) (in-place into attn); out = LN(h + neuron_out) ----
  k_ln_res<<<4096,256,0,stream>>>(x, attn, g1, be1, attn);
  k_ln_res<<<4096,256,0,stream>>>(attn, neuf, g2, be2, out);
}